// Round 4
// baseline (3262.479 us; speedup 1.0000x reference)
//
#include <hip/hip_runtime.h>

#define NN 100000
#define NE 1600000
#define DD 128
#define NG 128
#define NC 10
#define BK 128                      // nodes per bucket
#define NB ((NN + BK - 1) / BK)     // 782 buckets
#define POOL_WAVES 2048

// ---------------- degree histogram ----------------
__global__ __launch_bounds__(256) void deg_k(const int* __restrict__ col, int* __restrict__ degi) {
    int e = blockIdx.x * 256 + threadIdx.x;
    if (e < NE) atomicAdd(&degi[col[e]], 1);
}

// ---------------- dinv + per-bucket edge counts (block = bucket) ----------------
__global__ __launch_bounds__(128) void dinv_bsum_k(const int* __restrict__ degi, float* __restrict__ dinv,
                                                   int* __restrict__ bcnt) {
    __shared__ int red[128];
    int b = blockIdx.x;
    int t = threadIdx.x;
    int i = b * BK + t;
    int dg = 0;
    if (i < NN) {
        dg = degi[i];
        dinv[i] = rsqrtf((float)dg + 1.0f);  // +1 self-loop
    }
    red[t] = dg;
    __syncthreads();
    for (int o = 64; o > 0; o >>= 1) {
        if (t < o) red[t] += red[t + o];
        __syncthreads();
    }
    if (t == 0) bcnt[b] = red[0];
}

// ---------------- scan bucket counts -> bbase, init cursors (1 block) ----------------
__global__ __launch_bounds__(1024) void bscan_k(const int* __restrict__ bcnt, int* __restrict__ bbase,
                                                int* __restrict__ cursor) {
    __shared__ int tmp[1024];
    int t = threadIdx.x;
    int v = (t < NB) ? bcnt[t] : 0;
    tmp[t] = v;
    __syncthreads();
    for (int o = 1; o < 1024; o <<= 1) {
        int u = (t >= o) ? tmp[t - o] : 0;
        __syncthreads();
        tmp[t] += u;
        __syncthreads();
    }
    if (t < NB) {
        int ex = tmp[t] - v;
        bbase[t] = ex;
        cursor[t] = ex;
    }
    if (t == 1023) bbase[NB] = tmp[1023];  // == NE
}

// ---------------- bucket fill: scatter with only NB frontiers (L2-merged writes) ----------------
__global__ __launch_bounds__(256) void bucket_fill_k(const int* __restrict__ row, const int* __restrict__ col,
                                                     int* __restrict__ cursor, int* __restrict__ bucketarr) {
    int e = blockIdx.x * 256 + threadIdx.x;
    if (e < NE) {
        int c = col[e];
        int b = c >> 7;
        int pos = atomicAdd(&cursor[b], 1);
        bucketarr[pos] = (row[e] << 7) | (c & 127);
    }
}

// ---------------- GEMM: out[r][:] = dinv[r] * (X[r][:] @ W)  (128x128 W) ----------------
__global__ __launch_bounds__(256) void gemm_scaled_k(const float* __restrict__ X,
                                                     const float* __restrict__ W,
                                                     const float* __restrict__ dinv,
                                                     float* __restrict__ out) {
    __shared__ float xs[32 * 130];
    int tid = threadIdx.x;
    long base = (long)blockIdx.x * 32 * DD;
#pragma unroll
    for (int i = 0; i < 16; ++i) {
        int idx = tid + i * 256;
        int r = idx >> 7, k = idx & 127;
        xs[r * 130 + k] = X[base + idx];
    }
    __syncthreads();
    int cg = tid & 31;   // cols 4cg..4cg+3
    int rg = tid >> 5;   // rows 4rg..4rg+3
    const float4* W4 = (const float4*)W;
    float4 a0 = {0, 0, 0, 0}, a1 = {0, 0, 0, 0}, a2 = {0, 0, 0, 0}, a3 = {0, 0, 0, 0};
    const float* x0p = xs + (4 * rg + 0) * 130;
    const float* x1p = xs + (4 * rg + 1) * 130;
    const float* x2p = xs + (4 * rg + 2) * 130;
    const float* x3p = xs + (4 * rg + 3) * 130;
#pragma unroll 8
    for (int k = 0; k < DD; ++k) {
        float4 w = W4[k * 32 + cg];
        float x0 = x0p[k], x1 = x1p[k], x2 = x2p[k], x3 = x3p[k];
        a0.x = fmaf(x0, w.x, a0.x); a0.y = fmaf(x0, w.y, a0.y);
        a0.z = fmaf(x0, w.z, a0.z); a0.w = fmaf(x0, w.w, a0.w);
        a1.x = fmaf(x1, w.x, a1.x); a1.y = fmaf(x1, w.y, a1.y);
        a1.z = fmaf(x1, w.z, a1.z); a1.w = fmaf(x1, w.w, a1.w);
        a2.x = fmaf(x2, w.x, a2.x); a2.y = fmaf(x2, w.y, a2.y);
        a2.z = fmaf(x2, w.z, a2.z); a2.w = fmaf(x2, w.w, a2.w);
        a3.x = fmaf(x3, w.x, a3.x); a3.y = fmaf(x3, w.y, a3.y);
        a3.z = fmaf(x3, w.z, a3.z); a3.w = fmaf(x3, w.w, a3.w);
    }
    int row = blockIdx.x * 32 + 4 * rg;
    float d;
    float4* o;
    d = dinv[row + 0]; o = (float4*)(out + (long)(row + 0) * DD);
    o[cg] = make_float4(d * a0.x, d * a0.y, d * a0.z, d * a0.w);
    d = dinv[row + 1]; o = (float4*)(out + (long)(row + 1) * DD);
    o[cg] = make_float4(d * a1.x, d * a1.y, d * a1.z, d * a1.w);
    d = dinv[row + 2]; o = (float4*)(out + (long)(row + 2) * DD);
    o[cg] = make_float4(d * a2.x, d * a2.y, d * a2.z, d * a2.w);
    d = dinv[row + 3]; o = (float4*)(out + (long)(row + 3) * DD);
    o[cg] = make_float4(d * a3.x, d * a3.y, d * a3.z, d * a3.w);
}

// ---------------- fused aggregation: block = bucket, LDS 128x128 acc tile ----------------
// out[i] = relu(dinv[i]*(sum_{src->i} h'[src] + h'[i]) + b)
__global__ __launch_bounds__(512) void agg_fused_k(const float* __restrict__ hp, const float* __restrict__ dinv,
                                                   const int* __restrict__ bbase, const int* __restrict__ bucketarr,
                                                   const float* __restrict__ bias, float* __restrict__ out) {
    __shared__ float acc[BK * DD];  // 64 KB
    int tid = threadIdx.x;
    float4* a4 = (float4*)acc;
#pragma unroll
    for (int i = 0; i < BK * DD / 4 / 512; ++i) a4[tid + i * 512] = make_float4(0, 0, 0, 0);
    __syncthreads();

    int b = blockIdx.x;
    int ebeg = bbase[b], eend = bbase[b + 1];
    int wave = tid >> 6, lane = tid & 63;
    const float2* hp2 = (const float2*)hp;

    int e = ebeg + wave;
    for (; e + 8 < eend; e += 16) {  // unroll 2 (8 waves stride)
        int p0 = bucketarr[e];
        int p1 = bucketarr[e + 8];
        float2 v0 = hp2[(long)(p0 >> 7) * 64 + lane];
        float2 v1 = hp2[(long)(p1 >> 7) * 64 + lane];
        int c0 = p0 & 127, c1 = p1 & 127;
        atomicAdd(&acc[c0 * DD + 2 * lane], v0.x);
        atomicAdd(&acc[c0 * DD + 2 * lane + 1], v0.y);
        atomicAdd(&acc[c1 * DD + 2 * lane], v1.x);
        atomicAdd(&acc[c1 * DD + 2 * lane + 1], v1.y);
    }
    for (; e < eend; e += 8) {
        int p0 = bucketarr[e];
        float2 v0 = hp2[(long)(p0 >> 7) * 64 + lane];
        int c0 = p0 & 127;
        atomicAdd(&acc[c0 * DD + 2 * lane], v0.x);
        atomicAdd(&acc[c0 * DD + 2 * lane + 1], v0.y);
    }
    __syncthreads();

    int n0 = b * BK;
    int nmax = min(BK, NN - n0);
    int r = tid >> 7;   // 0..3
    int d = tid & 127;
    for (int rr = r; rr < nmax; rr += 4) {
        int node = n0 + rr;
        float self = hp[(long)node * DD + d];
        float val = fmaf(dinv[node], acc[rr * DD + d] + self, bias[d]);
        out[(long)node * DD + d] = fmaxf(val, 0.0f);
    }
}

// ---------------- pooling: 2048 waves over sorted batch, boundary-flush atomics ----------------
__global__ __launch_bounds__(256) void pool2_k(const float* __restrict__ h, const int* __restrict__ batch,
                                               float* __restrict__ gsum) {
    int wave = (blockIdx.x * 256 + threadIdx.x) >> 6;
    int lane = threadIdx.x & 63;
    const int per = (NN + POOL_WAVES - 1) / POOL_WAVES;  // 49
    int s = wave * per;
    int e = min(s + per, NN);
    if (s >= e) return;
    const float2* h2 = (const float2*)h;
    float2 acc = {0.0f, 0.0f};
    int cur = batch[s];
    for (int r = s; r < e; ++r) {
        int b = batch[r];
        if (b != cur) {
            atomicAdd(&gsum[cur * DD + 2 * lane], acc.x);
            atomicAdd(&gsum[cur * DD + 2 * lane + 1], acc.y);
            acc.x = 0.0f; acc.y = 0.0f;
            cur = b;
        }
        float2 v = h2[(long)r * 64 + lane];
        acc.x += v.x;
        acc.y += v.y;
    }
    atomicAdd(&gsum[cur * DD + 2 * lane], acc.x);
    atomicAdd(&gsum[cur * DD + 2 * lane + 1], acc.y);
}

// ---------------- graph boundaries (batch sorted) ----------------
__global__ __launch_bounds__(256) void starts_k(const int* __restrict__ batch, int* __restrict__ starts) {
    int g = threadIdx.x;
    if (g > NG) return;
    if (g == NG) {
        starts[NG] = NN;
        return;
    }
    int lo = 0, hi = NN;
    while (lo < hi) {
        int mid = (lo + hi) >> 1;
        if (batch[mid] < g) lo = mid + 1;
        else hi = mid;
    }
    starts[g] = lo;
}

__global__ __launch_bounds__(256) void final_k(const float* __restrict__ gsum, const int* __restrict__ starts,
                                               const float* __restrict__ Wlin, const float* __restrict__ blin,
                                               float* __restrict__ out) {
    int idx = blockIdx.x * 256 + threadIdx.x;
    if (idx >= NG * NC) return;
    int g = idx / NC, c = idx % NC;
    int cnt = starts[g + 1] - starts[g];
    float inv = 1.0f / fmaxf((float)cnt, 1.0f);
    float acc = blin[c];
    for (int k = 0; k < DD; ++k) acc = fmaf(gsum[g * DD + k] * inv, Wlin[k * NC + c], acc);
    out[idx] = acc;
}

extern "C" void kernel_launch(void* const* d_in, const int* in_sizes, int n_in,
                              void* d_out, int out_size, void* d_ws, size_t ws_size,
                              hipStream_t stream) {
    const float* x     = (const float*)d_in[0];
    const int*   ei    = (const int*)d_in[1];   // [2][NE]: row=src, col=dst
    const int*   batch = (const int*)d_in[2];
    const float* W1    = (const float*)d_in[3];
    const float* b1    = (const float*)d_in[4];
    const float* W2    = (const float*)d_in[5];
    const float* b2    = (const float*)d_in[6];
    const float* Wlin  = (const float*)d_in[7];
    const float* blin  = (const float*)d_in[8];
    float* out = (float*)d_out;

    const int* erow = ei;
    const int* ecol = ei + NE;

    char* ws = (char*)d_ws;
    size_t off = 0;
    auto alloc = [&](size_t bytes) {
        void* p = ws + off;
        off = (off + bytes + 255) & ~(size_t)255;
        return p;
    };
    float* bufA      = (float*)alloc((size_t)NN * DD * 4);  // h' (scaled transform)
    float* bufB      = (float*)alloc((size_t)NN * DD * 4);  // layer output
    float* dinv      = (float*)alloc(NN * 4);
    int*   degi      = (int*)alloc(NN * 4);
    int*   bcnt      = (int*)alloc(NB * 4);
    int*   bbase     = (int*)alloc((NB + 1) * 4);
    int*   cursor    = (int*)alloc(NB * 4);
    int*   bucketarr = (int*)alloc((size_t)NE * 4);
    float* gsum      = (float*)alloc(NG * DD * 4);
    int*   starts    = (int*)alloc((NG + 1) * 4);
    (void)ws_size;

    hipMemsetAsync(degi, 0, NN * 4, stream);
    hipMemsetAsync(gsum, 0, NG * DD * 4, stream);

    deg_k<<<(NE + 255) / 256, 256, 0, stream>>>(ecol, degi);
    dinv_bsum_k<<<NB, 128, 0, stream>>>(degi, dinv, bcnt);
    bscan_k<<<1, 1024, 0, stream>>>(bcnt, bbase, cursor);
    bucket_fill_k<<<(NE + 255) / 256, 256, 0, stream>>>(erow, ecol, cursor, bucketarr);

    // layer 1: x -> bufA (scaled transform) -> bufB (aggregated + relu)
    gemm_scaled_k<<<NN / 32, 256, 0, stream>>>(x, W1, dinv, bufA);
    agg_fused_k<<<NB, 512, 0, stream>>>(bufA, dinv, bbase, bucketarr, b1, bufB);
    // layer 2: bufB -> bufA -> bufB
    gemm_scaled_k<<<NN / 32, 256, 0, stream>>>(bufB, W2, dinv, bufA);
    agg_fused_k<<<NB, 512, 0, stream>>>(bufA, dinv, bbase, bucketarr, b2, bufB);

    // pooling + head
    starts_k<<<1, 256, 0, stream>>>(batch, starts);
    pool2_k<<<POOL_WAVES / 4, 256, 0, stream>>>(bufB, batch, gsum);
    final_k<<<(NG * NC + 255) / 256, 256, 0, stream>>>(gsum, starts, Wlin, blin, out);
}

// Round 5
// 865.355 us; speedup vs baseline: 3.7701x; 3.7701x over previous
//
#include <hip/hip_runtime.h>

#define NN 100000
#define NE 1600000
#define DD 128
#define NG 128
#define NC 10
#define BK 128                      // nodes per bucket
#define NB ((NN + BK - 1) / BK)     // 782 buckets
#define POOL_WAVES 2048

// ---------------- degree histogram ----------------
__global__ __launch_bounds__(256) void deg_k(const int* __restrict__ col, int* __restrict__ degi) {
    int e = blockIdx.x * 256 + threadIdx.x;
    if (e < NE) atomicAdd(&degi[col[e]], 1);
}

// ---------------- dinv + per-bucket edge counts (block = bucket) ----------------
__global__ __launch_bounds__(128) void dinv_bsum_k(const int* __restrict__ degi, float* __restrict__ dinv,
                                                   int* __restrict__ bcnt) {
    __shared__ int red[128];
    int b = blockIdx.x;
    int t = threadIdx.x;
    int i = b * BK + t;
    int dg = 0;
    if (i < NN) {
        dg = degi[i];
        dinv[i] = rsqrtf((float)dg + 1.0f);  // +1 self-loop
    }
    red[t] = dg;
    __syncthreads();
    for (int o = 64; o > 0; o >>= 1) {
        if (t < o) red[t] += red[t + o];
        __syncthreads();
    }
    if (t == 0) bcnt[b] = red[0];
}

// ---------------- scan bucket counts -> bbase, init bucket cursors (1 block) ----------------
__global__ __launch_bounds__(1024) void bscan_k(const int* __restrict__ bcnt, int* __restrict__ bbase,
                                                int* __restrict__ cursor) {
    __shared__ int tmp[1024];
    int t = threadIdx.x;
    int v = (t < NB) ? bcnt[t] : 0;
    tmp[t] = v;
    __syncthreads();
    for (int o = 1; o < 1024; o <<= 1) {
        int u = (t >= o) ? tmp[t - o] : 0;
        __syncthreads();
        tmp[t] += u;
        __syncthreads();
    }
    if (t < NB) {
        int ex = tmp[t] - v;
        bbase[t] = ex;
        cursor[t] = ex;
    }
    if (t == 1023) bbase[NB] = tmp[1023];  // == NE
}

// ---------------- bucket fill: scatter with only NB frontiers (L2-merged writes) ----------------
__global__ __launch_bounds__(256) void bucket_fill_k(const int* __restrict__ row, const int* __restrict__ col,
                                                     int* __restrict__ cursor, int* __restrict__ bucketarr) {
    int e = blockIdx.x * 256 + threadIdx.x;
    if (e < NE) {
        int c = col[e];
        int b = c >> 7;
        int pos = atomicAdd(&cursor[b], 1);
        bucketarr[pos] = (row[e] << 7) | (c & 127);
    }
}

// ---------------- bucket -> per-node CSR (block = bucket; writes stay in one 8KB region) ----
__global__ __launch_bounds__(256) void csr_build_k(const int* __restrict__ degi, const int* __restrict__ bbase,
                                                   const int* __restrict__ bucketarr,
                                                   int* __restrict__ offs, int* __restrict__ csr_src) {
    __shared__ int loff[BK];   // inclusive scan of bucket-local degrees
    __shared__ int lcur[BK];   // bucket-local cursors
    int b = blockIdx.x, t = threadIdx.x;
    int n0 = b * BK;
    int d = 0;
    if (t < BK) {
        int node = n0 + t;
        d = (node < NN) ? degi[node] : 0;
        loff[t] = d;
    }
    __syncthreads();
    for (int o = 1; o < BK; o <<= 1) {
        int v = (t < BK && t >= o) ? loff[t - o] : 0;
        __syncthreads();
        if (t < BK) loff[t] += v;
        __syncthreads();
    }
    int ebeg = bbase[b], eend = bbase[b + 1];
    if (t < BK) {
        int excl = loff[t] - d;
        lcur[t] = excl;
        int node = n0 + t;
        if (node < NN) offs[node] = ebeg + excl;
    }
    if (b == NB - 1 && t == 0) offs[NN] = NE;
    __syncthreads();
    for (int e = ebeg + t; e < eend; e += 256) {
        int p = bucketarr[e];
        int pos = atomicAdd(&lcur[p & 127], 1);
        csr_src[ebeg + pos] = p >> 7;
    }
}

// ---------------- GEMM: out[r][:] = dinv[r] * (X[r][:] @ W)  (128x128 W) ----------------
__global__ __launch_bounds__(256) void gemm_scaled_k(const float* __restrict__ X,
                                                     const float* __restrict__ W,
                                                     const float* __restrict__ dinv,
                                                     float* __restrict__ out) {
    __shared__ float xs[32 * 130];
    int tid = threadIdx.x;
    long base = (long)blockIdx.x * 32 * DD;
#pragma unroll
    for (int i = 0; i < 16; ++i) {
        int idx = tid + i * 256;
        int r = idx >> 7, k = idx & 127;
        xs[r * 130 + k] = X[base + idx];
    }
    __syncthreads();
    int cg = tid & 31;   // cols 4cg..4cg+3
    int rg = tid >> 5;   // rows 4rg..4rg+3
    const float4* W4 = (const float4*)W;
    float4 a0 = {0, 0, 0, 0}, a1 = {0, 0, 0, 0}, a2 = {0, 0, 0, 0}, a3 = {0, 0, 0, 0};
    const float* x0p = xs + (4 * rg + 0) * 130;
    const float* x1p = xs + (4 * rg + 1) * 130;
    const float* x2p = xs + (4 * rg + 2) * 130;
    const float* x3p = xs + (4 * rg + 3) * 130;
#pragma unroll 8
    for (int k = 0; k < DD; ++k) {
        float4 w = W4[k * 32 + cg];
        float x0 = x0p[k], x1 = x1p[k], x2 = x2p[k], x3 = x3p[k];
        a0.x = fmaf(x0, w.x, a0.x); a0.y = fmaf(x0, w.y, a0.y);
        a0.z = fmaf(x0, w.z, a0.z); a0.w = fmaf(x0, w.w, a0.w);
        a1.x = fmaf(x1, w.x, a1.x); a1.y = fmaf(x1, w.y, a1.y);
        a1.z = fmaf(x1, w.z, a1.z); a1.w = fmaf(x1, w.w, a1.w);
        a2.x = fmaf(x2, w.x, a2.x); a2.y = fmaf(x2, w.y, a2.y);
        a2.z = fmaf(x2, w.z, a2.z); a2.w = fmaf(x2, w.w, a2.w);
        a3.x = fmaf(x3, w.x, a3.x); a3.y = fmaf(x3, w.y, a3.y);
        a3.z = fmaf(x3, w.z, a3.z); a3.w = fmaf(x3, w.w, a3.w);
    }
    int row = blockIdx.x * 32 + 4 * rg;
    float d;
    float4* o;
    d = dinv[row + 0]; o = (float4*)(out + (long)(row + 0) * DD);
    o[cg] = make_float4(d * a0.x, d * a0.y, d * a0.z, d * a0.w);
    d = dinv[row + 1]; o = (float4*)(out + (long)(row + 1) * DD);
    o[cg] = make_float4(d * a1.x, d * a1.y, d * a1.z, d * a1.w);
    d = dinv[row + 2]; o = (float4*)(out + (long)(row + 2) * DD);
    o[cg] = make_float4(d * a2.x, d * a2.y, d * a2.z, d * a2.w);
    d = dinv[row + 3]; o = (float4*)(out + (long)(row + 3) * DD);
    o[cg] = make_float4(d * a3.x, d * a3.y, d * a3.z, d * a3.w);
}

// ---------------- aggregation: wave per node, unroll 4 ----------------
// out[i] = relu(dinv[i]*(sum_{src in CSR[i]} h[src] + h[i]) + b)
__global__ __launch_bounds__(256) void agg_k(const float* __restrict__ hp, const float* __restrict__ dinv,
                                             const int* __restrict__ offs, const int* __restrict__ csr_src,
                                             const float* __restrict__ bias, float* __restrict__ out) {
    int node = (blockIdx.x << 2) + (threadIdx.x >> 6);
    if (node >= NN) return;
    int lane = threadIdx.x & 63;
    const float2* hp2 = (const float2*)hp;
    int s = offs[node];
    int e_end = offs[node + 1];
    float2 acc = hp2[(long)node * 64 + lane];  // self-loop contribution
    int e = s;
    for (; e + 4 <= e_end; e += 4) {
        int s0 = csr_src[e];
        int s1 = csr_src[e + 1];
        int s2 = csr_src[e + 2];
        int s3 = csr_src[e + 3];
        float2 v0 = hp2[(long)s0 * 64 + lane];
        float2 v1 = hp2[(long)s1 * 64 + lane];
        float2 v2 = hp2[(long)s2 * 64 + lane];
        float2 v3 = hp2[(long)s3 * 64 + lane];
        acc.x += (v0.x + v1.x) + (v2.x + v3.x);
        acc.y += (v0.y + v1.y) + (v2.y + v3.y);
    }
    for (; e < e_end; ++e) {
        int s0 = csr_src[e];
        float2 v0 = hp2[(long)s0 * 64 + lane];
        acc.x += v0.x;
        acc.y += v0.y;
    }
    float dv = dinv[node];
    float2 b = ((const float2*)bias)[lane];
    float2 o;
    o.x = fmaxf(fmaf(dv, acc.x, b.x), 0.0f);
    o.y = fmaxf(fmaf(dv, acc.y, b.y), 0.0f);
    ((float2*)out)[(long)node * 64 + lane] = o;
}

// ---------------- pooling: 2048 waves over sorted batch, boundary-flush atomics ----------------
__global__ __launch_bounds__(256) void pool2_k(const float* __restrict__ h, const int* __restrict__ batch,
                                               float* __restrict__ gsum) {
    int wave = (blockIdx.x * 256 + threadIdx.x) >> 6;
    int lane = threadIdx.x & 63;
    const int per = (NN + POOL_WAVES - 1) / POOL_WAVES;  // 49
    int s = wave * per;
    int e = min(s + per, NN);
    if (s >= e) return;
    const float2* h2 = (const float2*)h;
    float2 acc = {0.0f, 0.0f};
    int cur = batch[s];
    for (int r = s; r < e; ++r) {
        int b = batch[r];
        if (b != cur) {
            atomicAdd(&gsum[cur * DD + 2 * lane], acc.x);
            atomicAdd(&gsum[cur * DD + 2 * lane + 1], acc.y);
            acc.x = 0.0f; acc.y = 0.0f;
            cur = b;
        }
        float2 v = h2[(long)r * 64 + lane];
        acc.x += v.x;
        acc.y += v.y;
    }
    atomicAdd(&gsum[cur * DD + 2 * lane], acc.x);
    atomicAdd(&gsum[cur * DD + 2 * lane + 1], acc.y);
}

// ---------------- graph boundaries (batch sorted) ----------------
__global__ __launch_bounds__(256) void starts_k(const int* __restrict__ batch, int* __restrict__ starts) {
    int g = threadIdx.x;
    if (g > NG) return;
    if (g == NG) {
        starts[NG] = NN;
        return;
    }
    int lo = 0, hi = NN;
    while (lo < hi) {
        int mid = (lo + hi) >> 1;
        if (batch[mid] < g) lo = mid + 1;
        else hi = mid;
    }
    starts[g] = lo;
}

__global__ __launch_bounds__(256) void final_k(const float* __restrict__ gsum, const int* __restrict__ starts,
                                               const float* __restrict__ Wlin, const float* __restrict__ blin,
                                               float* __restrict__ out) {
    int idx = blockIdx.x * 256 + threadIdx.x;
    if (idx >= NG * NC) return;
    int g = idx / NC, c = idx % NC;
    int cnt = starts[g + 1] - starts[g];
    float inv = 1.0f / fmaxf((float)cnt, 1.0f);
    float acc = blin[c];
    for (int k = 0; k < DD; ++k) acc = fmaf(gsum[g * DD + k] * inv, Wlin[k * NC + c], acc);
    out[idx] = acc;
}

extern "C" void kernel_launch(void* const* d_in, const int* in_sizes, int n_in,
                              void* d_out, int out_size, void* d_ws, size_t ws_size,
                              hipStream_t stream) {
    const float* x     = (const float*)d_in[0];
    const int*   ei    = (const int*)d_in[1];   // [2][NE]: row=src, col=dst
    const int*   batch = (const int*)d_in[2];
    const float* W1    = (const float*)d_in[3];
    const float* b1    = (const float*)d_in[4];
    const float* W2    = (const float*)d_in[5];
    const float* b2    = (const float*)d_in[6];
    const float* Wlin  = (const float*)d_in[7];
    const float* blin  = (const float*)d_in[8];
    float* out = (float*)d_out;

    const int* erow = ei;
    const int* ecol = ei + NE;

    char* ws = (char*)d_ws;
    size_t off = 0;
    auto alloc = [&](size_t bytes) {
        void* p = ws + off;
        off = (off + bytes + 255) & ~(size_t)255;
        return p;
    };
    float* bufA      = (float*)alloc((size_t)NN * DD * 4);  // h' (scaled transform)
    float* bufB      = (float*)alloc((size_t)NN * DD * 4);  // layer output
    float* dinv      = (float*)alloc(NN * 4);
    int*   degi      = (int*)alloc(NN * 4);
    int*   bcnt      = (int*)alloc(NB * 4);
    int*   bbase     = (int*)alloc((NB + 1) * 4);
    int*   cursor    = (int*)alloc(NB * 4);
    int*   bucketarr = (int*)alloc((size_t)NE * 4);
    int*   offs      = (int*)alloc((NN + 1) * 4);
    int*   csrsrc    = (int*)alloc((size_t)NE * 4);
    float* gsum      = (float*)alloc(NG * DD * 4);
    int*   starts    = (int*)alloc((NG + 1) * 4);
    (void)ws_size;

    hipMemsetAsync(degi, 0, NN * 4, stream);
    hipMemsetAsync(gsum, 0, NG * DD * 4, stream);

    deg_k<<<(NE + 255) / 256, 256, 0, stream>>>(ecol, degi);
    dinv_bsum_k<<<NB, 128, 0, stream>>>(degi, dinv, bcnt);
    bscan_k<<<1, 1024, 0, stream>>>(bcnt, bbase, cursor);
    bucket_fill_k<<<(NE + 255) / 256, 256, 0, stream>>>(erow, ecol, cursor, bucketarr);
    csr_build_k<<<NB, 256, 0, stream>>>(degi, bbase, bucketarr, offs, csrsrc);

    // layer 1: x -> bufA (scaled transform) -> bufB (aggregated + relu)
    gemm_scaled_k<<<NN / 32, 256, 0, stream>>>(x, W1, dinv, bufA);
    agg_k<<<(NN + 3) / 4, 256, 0, stream>>>(bufA, dinv, offs, csrsrc, b1, bufB);
    // layer 2: bufB -> bufA -> bufB
    gemm_scaled_k<<<NN / 32, 256, 0, stream>>>(bufB, W2, dinv, bufA);
    agg_k<<<(NN + 3) / 4, 256, 0, stream>>>(bufA, dinv, offs, csrsrc, b2, bufB);

    // pooling + head
    starts_k<<<1, 256, 0, stream>>>(batch, starts);
    pool2_k<<<POOL_WAVES / 4, 256, 0, stream>>>(bufB, batch, gsum);
    final_k<<<(NG * NC + 255) / 256, 256, 0, stream>>>(gsum, starts, Wlin, blin, out);
}

// Round 6
// 594.546 us; speedup vs baseline: 5.4873x; 1.4555x over previous
//
#include <hip/hip_runtime.h>

#define NN 100000
#define NE 1600000
#define DD 128
#define NG 128
#define NC 10
#define NB8 (NN / 8)                // 12500 buckets of 8 nodes
#define SCAN_ELEMS 1024
#define NSCAN ((NN + SCAN_ELEMS - 1) / SCAN_ELEMS)  // 98
#define POOL_WAVES 2048

// ---------------- degree histogram ----------------
__global__ __launch_bounds__(256) void deg_k(const int* __restrict__ col, int* __restrict__ degi) {
    int e = blockIdx.x * 256 + threadIdx.x;
    if (e < NE) atomicAdd(&degi[col[e]], 1);
}

__global__ __launch_bounds__(256) void dinv_k(const int* __restrict__ degi, float* __restrict__ dinv) {
    int i = blockIdx.x * 256 + threadIdx.x;
    if (i < NN) dinv[i] = rsqrtf((float)degi[i] + 1.0f);  // +1 self-loop
}

// ---------------- exclusive scan of degi -> offs ----------------
__global__ __launch_bounds__(256) void scan1_k(const int* __restrict__ degi, int* __restrict__ offs,
                                               int* __restrict__ partials) {
    __shared__ int tmp[256];
    int tid = threadIdx.x;
    int base = blockIdx.x * SCAN_ELEMS + tid * 4;
    int v[4];
    int s = 0;
#pragma unroll
    for (int j = 0; j < 4; ++j) {
        int idx = base + j;
        v[j] = (idx < NN) ? degi[idx] : 0;
        s += v[j];
    }
    tmp[tid] = s;
    __syncthreads();
    for (int off = 1; off < 256; off <<= 1) {
        int t = (tid >= off) ? tmp[tid - off] : 0;
        __syncthreads();
        tmp[tid] += t;
        __syncthreads();
    }
    int excl = tmp[tid] - s;
    int run = excl;
#pragma unroll
    for (int j = 0; j < 4; ++j) {
        int idx = base + j;
        if (idx < NN) offs[idx] = run;
        run += v[j];
    }
    if (tid == 255) partials[blockIdx.x] = tmp[255];
}

__global__ __launch_bounds__(128) void scan2_k(const int* __restrict__ partials, int* __restrict__ psc) {
    __shared__ int tmp[128];
    int tid = threadIdx.x;
    int v = (tid < NSCAN) ? partials[tid] : 0;
    tmp[tid] = v;
    __syncthreads();
    for (int off = 1; off < 128; off <<= 1) {
        int t = (tid >= off) ? tmp[tid - off] : 0;
        __syncthreads();
        tmp[tid] += t;
        __syncthreads();
    }
    int excl = tmp[tid] - v;
    if (tid < NSCAN) psc[tid] = excl;
    if (tid == 127) psc[NSCAN] = tmp[127];  // total (== NE)
}

// add block offsets; init per-bucket cursors (padded: one cursor per 64B line)
__global__ __launch_bounds__(256) void scan3_k(int* __restrict__ offs, int* __restrict__ cursor,
                                               const int* __restrict__ psc) {
    int i = blockIdx.x * 256 + threadIdx.x;
    if (i < NN) {
        int v = offs[i] + psc[i >> 10];
        offs[i] = v;
        if ((i & 7) == 0) cursor[(i >> 3) << 4] = v;  // cursor[b*16], line-padded
        if (i == 0) offs[NN] = psc[NSCAN];
    }
}

// ---------------- bucket fill: 12.5K line-padded frontiers ----------------
__global__ __launch_bounds__(256) void bucket8_fill_k(const int* __restrict__ row, const int* __restrict__ col,
                                                      int* __restrict__ cursor, int* __restrict__ bucketarr) {
    int e = blockIdx.x * 256 + threadIdx.x;
    if (e < NE) {
        int c = col[e];
        int b = c >> 3;
        int pos = atomicAdd(&cursor[b << 4], 1);
        bucketarr[pos] = (row[e] << 3) | (c & 7);  // row<2^17, fits 20 bits
    }
}

// ---------------- bucket -> exact per-node CSR (block per bucket, contiguous 8KB region) ----
__global__ __launch_bounds__(128) void csr_build8_k(const int* __restrict__ offs,
                                                    const int* __restrict__ bucketarr,
                                                    int* __restrict__ csr_src) {
    __shared__ int lcur[8];
    int b = blockIdx.x;
    int t = threadIdx.x;
    int n0 = b * 8;
    if (t < 8) lcur[t] = offs[n0 + t];
    __syncthreads();
    int ebeg = offs[n0];
    int eend = offs[n0 + 8];  // b==NB8-1 -> offs[NN] == NE
    for (int e = ebeg + t; e < eend; e += 128) {
        int p = bucketarr[e];
        int pos = atomicAdd(&lcur[p & 7], 1);
        csr_src[pos] = p >> 3;
    }
}

// ---------------- GEMM: out[r][:] = dinv[r] * (X[r][:] @ W)  (128x128 W) ----------------
__global__ __launch_bounds__(256) void gemm_scaled_k(const float* __restrict__ X,
                                                     const float* __restrict__ W,
                                                     const float* __restrict__ dinv,
                                                     float* __restrict__ out) {
    __shared__ float xs[32 * 130];
    int tid = threadIdx.x;
    long base = (long)blockIdx.x * 32 * DD;
#pragma unroll
    for (int i = 0; i < 16; ++i) {
        int idx = tid + i * 256;
        int r = idx >> 7, k = idx & 127;
        xs[r * 130 + k] = X[base + idx];
    }
    __syncthreads();
    int cg = tid & 31;   // cols 4cg..4cg+3
    int rg = tid >> 5;   // rows 4rg..4rg+3
    const float4* W4 = (const float4*)W;
    float4 a0 = {0, 0, 0, 0}, a1 = {0, 0, 0, 0}, a2 = {0, 0, 0, 0}, a3 = {0, 0, 0, 0};
    const float* x0p = xs + (4 * rg + 0) * 130;
    const float* x1p = xs + (4 * rg + 1) * 130;
    const float* x2p = xs + (4 * rg + 2) * 130;
    const float* x3p = xs + (4 * rg + 3) * 130;
#pragma unroll 8
    for (int k = 0; k < DD; ++k) {
        float4 w = W4[k * 32 + cg];
        float x0 = x0p[k], x1 = x1p[k], x2 = x2p[k], x3 = x3p[k];
        a0.x = fmaf(x0, w.x, a0.x); a0.y = fmaf(x0, w.y, a0.y);
        a0.z = fmaf(x0, w.z, a0.z); a0.w = fmaf(x0, w.w, a0.w);
        a1.x = fmaf(x1, w.x, a1.x); a1.y = fmaf(x1, w.y, a1.y);
        a1.z = fmaf(x1, w.z, a1.z); a1.w = fmaf(x1, w.w, a1.w);
        a2.x = fmaf(x2, w.x, a2.x); a2.y = fmaf(x2, w.y, a2.y);
        a2.z = fmaf(x2, w.z, a2.z); a2.w = fmaf(x2, w.w, a2.w);
        a3.x = fmaf(x3, w.x, a3.x); a3.y = fmaf(x3, w.y, a3.y);
        a3.z = fmaf(x3, w.z, a3.z); a3.w = fmaf(x3, w.w, a3.w);
    }
    int row = blockIdx.x * 32 + 4 * rg;
    float d;
    float4* o;
    d = dinv[row + 0]; o = (float4*)(out + (long)(row + 0) * DD);
    o[cg] = make_float4(d * a0.x, d * a0.y, d * a0.z, d * a0.w);
    d = dinv[row + 1]; o = (float4*)(out + (long)(row + 1) * DD);
    o[cg] = make_float4(d * a1.x, d * a1.y, d * a1.z, d * a1.w);
    d = dinv[row + 2]; o = (float4*)(out + (long)(row + 2) * DD);
    o[cg] = make_float4(d * a2.x, d * a2.y, d * a2.z, d * a2.w);
    d = dinv[row + 3]; o = (float4*)(out + (long)(row + 3) * DD);
    o[cg] = make_float4(d * a3.x, d * a3.y, d * a3.z, d * a3.w);
}

// ---------------- aggregation: wave per node, unroll 4 ----------------
__global__ __launch_bounds__(256) void agg_k(const float* __restrict__ hp, const float* __restrict__ dinv,
                                             const int* __restrict__ offs, const int* __restrict__ csr_src,
                                             const float* __restrict__ bias, float* __restrict__ out) {
    int node = (blockIdx.x << 2) + (threadIdx.x >> 6);
    if (node >= NN) return;
    int lane = threadIdx.x & 63;
    const float2* hp2 = (const float2*)hp;
    int s = offs[node];
    int e_end = offs[node + 1];
    float2 acc = hp2[(long)node * 64 + lane];  // self-loop contribution
    int e = s;
    for (; e + 4 <= e_end; e += 4) {
        int s0 = csr_src[e];
        int s1 = csr_src[e + 1];
        int s2 = csr_src[e + 2];
        int s3 = csr_src[e + 3];
        float2 v0 = hp2[(long)s0 * 64 + lane];
        float2 v1 = hp2[(long)s1 * 64 + lane];
        float2 v2 = hp2[(long)s2 * 64 + lane];
        float2 v3 = hp2[(long)s3 * 64 + lane];
        acc.x += (v0.x + v1.x) + (v2.x + v3.x);
        acc.y += (v0.y + v1.y) + (v2.y + v3.y);
    }
    for (; e < e_end; ++e) {
        int s0 = csr_src[e];
        float2 v0 = hp2[(long)s0 * 64 + lane];
        acc.x += v0.x;
        acc.y += v0.y;
    }
    float dv = dinv[node];
    float2 b = ((const float2*)bias)[lane];
    float2 o;
    o.x = fmaxf(fmaf(dv, acc.x, b.x), 0.0f);
    o.y = fmaxf(fmaf(dv, acc.y, b.y), 0.0f);
    ((float2*)out)[(long)node * 64 + lane] = o;
}

// ---------------- pooling: 2048 waves over sorted batch, boundary-flush atomics ----------------
__global__ __launch_bounds__(256) void pool2_k(const float* __restrict__ h, const int* __restrict__ batch,
                                               float* __restrict__ gsum) {
    int wave = (blockIdx.x * 256 + threadIdx.x) >> 6;
    int lane = threadIdx.x & 63;
    const int per = (NN + POOL_WAVES - 1) / POOL_WAVES;  // 49
    int s = wave * per;
    int e = min(s + per, NN);
    if (s >= e) return;
    const float2* h2 = (const float2*)h;
    float2 acc = {0.0f, 0.0f};
    int cur = batch[s];
    for (int r = s; r < e; ++r) {
        int b = batch[r];
        if (b != cur) {
            atomicAdd(&gsum[cur * DD + 2 * lane], acc.x);
            atomicAdd(&gsum[cur * DD + 2 * lane + 1], acc.y);
            acc.x = 0.0f; acc.y = 0.0f;
            cur = b;
        }
        float2 v = h2[(long)r * 64 + lane];
        acc.x += v.x;
        acc.y += v.y;
    }
    atomicAdd(&gsum[cur * DD + 2 * lane], acc.x);
    atomicAdd(&gsum[cur * DD + 2 * lane + 1], acc.y);
}

// ---------------- graph boundaries (batch sorted) ----------------
__global__ __launch_bounds__(256) void starts_k(const int* __restrict__ batch, int* __restrict__ starts) {
    int g = threadIdx.x;
    if (g > NG) return;
    if (g == NG) {
        starts[NG] = NN;
        return;
    }
    int lo = 0, hi = NN;
    while (lo < hi) {
        int mid = (lo + hi) >> 1;
        if (batch[mid] < g) lo = mid + 1;
        else hi = mid;
    }
    starts[g] = lo;
}

__global__ __launch_bounds__(256) void final_k(const float* __restrict__ gsum, const int* __restrict__ starts,
                                               const float* __restrict__ Wlin, const float* __restrict__ blin,
                                               float* __restrict__ out) {
    int idx = blockIdx.x * 256 + threadIdx.x;
    if (idx >= NG * NC) return;
    int g = idx / NC, c = idx % NC;
    int cnt = starts[g + 1] - starts[g];
    float inv = 1.0f / fmaxf((float)cnt, 1.0f);
    float acc = blin[c];
    for (int k = 0; k < DD; ++k) acc = fmaf(gsum[g * DD + k] * inv, Wlin[k * NC + c], acc);
    out[idx] = acc;
}

extern "C" void kernel_launch(void* const* d_in, const int* in_sizes, int n_in,
                              void* d_out, int out_size, void* d_ws, size_t ws_size,
                              hipStream_t stream) {
    const float* x     = (const float*)d_in[0];
    const int*   ei    = (const int*)d_in[1];   // [2][NE]: row=src, col=dst
    const int*   batch = (const int*)d_in[2];
    const float* W1    = (const float*)d_in[3];
    const float* b1    = (const float*)d_in[4];
    const float* W2    = (const float*)d_in[5];
    const float* b2    = (const float*)d_in[6];
    const float* Wlin  = (const float*)d_in[7];
    const float* blin  = (const float*)d_in[8];
    float* out = (float*)d_out;

    const int* erow = ei;
    const int* ecol = ei + NE;

    char* ws = (char*)d_ws;
    size_t off = 0;
    auto alloc = [&](size_t bytes) {
        void* p = ws + off;
        off = (off + bytes + 255) & ~(size_t)255;
        return p;
    };
    float* bufA      = (float*)alloc((size_t)NN * DD * 4);  // h' (scaled transform)
    float* bufB      = (float*)alloc((size_t)NN * DD * 4);  // layer output
    float* dinv      = (float*)alloc(NN * 4);
    int*   degi      = (int*)alloc(NN * 4);
    int*   offs      = (int*)alloc((NN + 1) * 4);
    int*   cursor    = (int*)alloc((size_t)NB8 * 16 * 4);   // line-padded cursors
    int*   bucketarr = (int*)alloc((size_t)NE * 4);
    int*   csrsrc    = (int*)alloc((size_t)NE * 4);
    int*   partials  = (int*)alloc(NSCAN * 4);
    int*   psc       = (int*)alloc((NSCAN + 1) * 4);
    float* gsum      = (float*)alloc(NG * DD * 4);
    int*   starts    = (int*)alloc((NG + 1) * 4);
    (void)ws_size;

    hipMemsetAsync(degi, 0, NN * 4, stream);
    hipMemsetAsync(gsum, 0, NG * DD * 4, stream);

    deg_k<<<(NE + 255) / 256, 256, 0, stream>>>(ecol, degi);
    dinv_k<<<(NN + 255) / 256, 256, 0, stream>>>(degi, dinv);
    scan1_k<<<NSCAN, 256, 0, stream>>>(degi, offs, partials);
    scan2_k<<<1, 128, 0, stream>>>(partials, psc);
    scan3_k<<<(NN + 255) / 256, 256, 0, stream>>>(offs, cursor, psc);
    bucket8_fill_k<<<(NE + 255) / 256, 256, 0, stream>>>(erow, ecol, cursor, bucketarr);
    csr_build8_k<<<NB8, 128, 0, stream>>>(offs, bucketarr, csrsrc);

    // layer 1: x -> bufA (scaled transform) -> bufB (aggregated + relu)
    gemm_scaled_k<<<NN / 32, 256, 0, stream>>>(x, W1, dinv, bufA);
    agg_k<<<(NN + 3) / 4, 256, 0, stream>>>(bufA, dinv, offs, csrsrc, b1, bufB);
    // layer 2: bufB -> bufA -> bufB
    gemm_scaled_k<<<NN / 32, 256, 0, stream>>>(bufB, W2, dinv, bufA);
    agg_k<<<(NN + 3) / 4, 256, 0, stream>>>(bufA, dinv, offs, csrsrc, b2, bufB);

    // pooling + head
    starts_k<<<1, 256, 0, stream>>>(batch, starts);
    pool2_k<<<POOL_WAVES / 4, 256, 0, stream>>>(bufB, batch, gsum);
    final_k<<<(NG * NC + 255) / 256, 256, 0, stream>>>(gsum, starts, Wlin, blin, out);
}

// Round 7
// 517.090 us; speedup vs baseline: 6.3093x; 1.1498x over previous
//
#include <hip/hip_runtime.h>

#define NN 100000
#define NE 1600000
#define DD 128
#define NG 128
#define NC 10
#define SCAN_ELEMS 1024
#define NSCAN ((NN + SCAN_ELEMS - 1) / SCAN_ELEMS)  // 98
#define POOL_WAVES 2048

#define B1SH 8                        // coarse bucket = 256 nodes
#define NB1 ((NN + 255) / 256)        // 391 buckets
#define EPB 8192                      // edges per partition block
#define NWG1 ((NE + EPB - 1) / EPB)   // 196 partition blocks

// ---------------- degree histogram ----------------
__global__ __launch_bounds__(256) void deg_k(const int* __restrict__ col, int* __restrict__ degi) {
    int e = blockIdx.x * 256 + threadIdx.x;
    if (e < NE) atomicAdd(&degi[col[e]], 1);
}

__global__ __launch_bounds__(256) void dinv_k(const int* __restrict__ degi, float* __restrict__ dinv) {
    int i = blockIdx.x * 256 + threadIdx.x;
    if (i < NN) dinv[i] = rsqrtf((float)degi[i] + 1.0f);  // +1 self-loop
}

// ---------------- exclusive scan of degi -> offs ----------------
__global__ __launch_bounds__(256) void scan1_k(const int* __restrict__ degi, int* __restrict__ offs,
                                               int* __restrict__ partials) {
    __shared__ int tmp[256];
    int tid = threadIdx.x;
    int base = blockIdx.x * SCAN_ELEMS + tid * 4;
    int v[4];
    int s = 0;
#pragma unroll
    for (int j = 0; j < 4; ++j) {
        int idx = base + j;
        v[j] = (idx < NN) ? degi[idx] : 0;
        s += v[j];
    }
    tmp[tid] = s;
    __syncthreads();
    for (int off = 1; off < 256; off <<= 1) {
        int t = (tid >= off) ? tmp[tid - off] : 0;
        __syncthreads();
        tmp[tid] += t;
        __syncthreads();
    }
    int excl = tmp[tid] - s;
    int run = excl;
#pragma unroll
    for (int j = 0; j < 4; ++j) {
        int idx = base + j;
        if (idx < NN) offs[idx] = run;
        run += v[j];
    }
    if (tid == 255) partials[blockIdx.x] = tmp[255];
}

__global__ __launch_bounds__(128) void scan2_k(const int* __restrict__ partials, int* __restrict__ psc) {
    __shared__ int tmp[128];
    int tid = threadIdx.x;
    int v = (tid < NSCAN) ? partials[tid] : 0;
    tmp[tid] = v;
    __syncthreads();
    for (int off = 1; off < 128; off <<= 1) {
        int t = (tid >= off) ? tmp[tid - off] : 0;
        __syncthreads();
        tmp[tid] += t;
        __syncthreads();
    }
    int excl = tmp[tid] - v;
    if (tid < NSCAN) psc[tid] = excl;
    if (tid == 127) psc[NSCAN] = tmp[127];  // total (== NE)
}

__global__ __launch_bounds__(256) void scan3_k(int* __restrict__ offs, const int* __restrict__ psc) {
    int i = blockIdx.x * 256 + threadIdx.x;
    if (i < NN) {
        offs[i] += psc[i >> 10];
        if (i == 0) offs[NN] = psc[NSCAN];
    }
}

// ---------------- radix partition P1a: per-(wg,bucket) histogram ----------------
__global__ __launch_bounds__(256) void hist_k(const int* __restrict__ col, int* __restrict__ hist) {
    __shared__ int lh[NB1];
    int t = threadIdx.x, w = blockIdx.x;
    for (int i = t; i < NB1; i += 256) lh[i] = 0;
    __syncthreads();
    int base = w * EPB;
    int lim = min(base + EPB, NE);
#pragma unroll 4
    for (int e = base + t; e < lim; e += 256) atomicAdd(&lh[col[e] >> B1SH], 1);
    __syncthreads();
    for (int i = t; i < NB1; i += 256) hist[i * NWG1 + w] = lh[i];
}

// ---------------- P1b: per-bucket exclusive scan over wgs, seeded by offs[b*256] ----------------
__global__ __launch_bounds__(256) void histscan_k(const int* __restrict__ offs, int* __restrict__ hist) {
    __shared__ int tmp[256];
    int b = blockIdx.x, t = threadIdx.x;
    int v = (t < NWG1) ? hist[b * NWG1 + t] : 0;
    tmp[t] = v;
    __syncthreads();
    for (int o = 1; o < 256; o <<= 1) {
        int u = (t >= o) ? tmp[t - o] : 0;
        __syncthreads();
        tmp[t] += u;
        __syncthreads();
    }
    int excl = tmp[t] - v;
    if (t < NWG1) hist[b * NWG1 + t] = offs[b << B1SH] + excl;
}

// ---------------- P1c: partition edges into coarse-bucket segments (packed) ----------------
__global__ __launch_bounds__(256) void part1_k(const int* __restrict__ row, const int* __restrict__ col,
                                               const int* __restrict__ hist, int* __restrict__ tmpe) {
    __shared__ int lcur[NB1];
    int t = threadIdx.x, w = blockIdx.x;
    for (int i = t; i < NB1; i += 256) lcur[i] = hist[i * NWG1 + w];
    __syncthreads();
    int base = w * EPB;
    int lim = min(base + EPB, NE);
#pragma unroll 4
    for (int e = base + t; e < lim; e += 256) {
        int c = col[e];
        int pos = atomicAdd(&lcur[c >> B1SH], 1);
        tmpe[pos] = (row[e] << B1SH) | (c & 255);  // src<2^17 -> 25 bits
    }
}

// ---------------- P2: within-bucket scatter to exact per-node CSR (contiguous 16KB region) ----
__global__ __launch_bounds__(512) void part2_k(const int* __restrict__ offs, const int* __restrict__ tmpe,
                                               int* __restrict__ csr_src) {
    __shared__ int lcur[256];
    int b = blockIdx.x, t = threadIdx.x;
    int n0 = b << B1SH;
    for (int i = t; i < 256; i += 512) {
        int node = n0 + i;
        lcur[i] = (node < NN) ? offs[node] : 0;
    }
    __syncthreads();
    int ebeg = offs[n0];
    int eend = offs[min(n0 + 256, NN)];
#pragma unroll 4
    for (int e = ebeg + t; e < eend; e += 512) {
        int p = tmpe[e];
        int pos = atomicAdd(&lcur[p & 255], 1);
        csr_src[pos] = p >> B1SH;
    }
}

// ---------------- GEMM: out[r][:] = dinv[r] * (X[r][:] @ W)  (128x128 W) ----------------
__global__ __launch_bounds__(256) void gemm_scaled_k(const float* __restrict__ X,
                                                     const float* __restrict__ W,
                                                     const float* __restrict__ dinv,
                                                     float* __restrict__ out) {
    __shared__ float xs[32 * 130];
    int tid = threadIdx.x;
    long base = (long)blockIdx.x * 32 * DD;
#pragma unroll
    for (int i = 0; i < 16; ++i) {
        int idx = tid + i * 256;
        int r = idx >> 7, k = idx & 127;
        xs[r * 130 + k] = X[base + idx];
    }
    __syncthreads();
    int cg = tid & 31;   // cols 4cg..4cg+3
    int rg = tid >> 5;   // rows 4rg..4rg+3
    const float4* W4 = (const float4*)W;
    float4 a0 = {0, 0, 0, 0}, a1 = {0, 0, 0, 0}, a2 = {0, 0, 0, 0}, a3 = {0, 0, 0, 0};
    const float* x0p = xs + (4 * rg + 0) * 130;
    const float* x1p = xs + (4 * rg + 1) * 130;
    const float* x2p = xs + (4 * rg + 2) * 130;
    const float* x3p = xs + (4 * rg + 3) * 130;
#pragma unroll 8
    for (int k = 0; k < DD; ++k) {
        float4 w = W4[k * 32 + cg];
        float x0 = x0p[k], x1 = x1p[k], x2 = x2p[k], x3 = x3p[k];
        a0.x = fmaf(x0, w.x, a0.x); a0.y = fmaf(x0, w.y, a0.y);
        a0.z = fmaf(x0, w.z, a0.z); a0.w = fmaf(x0, w.w, a0.w);
        a1.x = fmaf(x1, w.x, a1.x); a1.y = fmaf(x1, w.y, a1.y);
        a1.z = fmaf(x1, w.z, a1.z); a1.w = fmaf(x1, w.w, a1.w);
        a2.x = fmaf(x2, w.x, a2.x); a2.y = fmaf(x2, w.y, a2.y);
        a2.z = fmaf(x2, w.z, a2.z); a2.w = fmaf(x2, w.w, a2.w);
        a3.x = fmaf(x3, w.x, a3.x); a3.y = fmaf(x3, w.y, a3.y);
        a3.z = fmaf(x3, w.z, a3.z); a3.w = fmaf(x3, w.w, a3.w);
    }
    int row = blockIdx.x * 32 + 4 * rg;
    float d;
    float4* o;
    d = dinv[row + 0]; o = (float4*)(out + (long)(row + 0) * DD);
    o[cg] = make_float4(d * a0.x, d * a0.y, d * a0.z, d * a0.w);
    d = dinv[row + 1]; o = (float4*)(out + (long)(row + 1) * DD);
    o[cg] = make_float4(d * a1.x, d * a1.y, d * a1.z, d * a1.w);
    d = dinv[row + 2]; o = (float4*)(out + (long)(row + 2) * DD);
    o[cg] = make_float4(d * a2.x, d * a2.y, d * a2.z, d * a2.w);
    d = dinv[row + 3]; o = (float4*)(out + (long)(row + 3) * DD);
    o[cg] = make_float4(d * a3.x, d * a3.y, d * a3.z, d * a3.w);
}

// ---------------- aggregation: wave per node, unroll 4 ----------------
__global__ __launch_bounds__(256) void agg_k(const float* __restrict__ hp, const float* __restrict__ dinv,
                                             const int* __restrict__ offs, const int* __restrict__ csr_src,
                                             const float* __restrict__ bias, float* __restrict__ out) {
    int node = (blockIdx.x << 2) + (threadIdx.x >> 6);
    if (node >= NN) return;
    int lane = threadIdx.x & 63;
    const float2* hp2 = (const float2*)hp;
    int s = offs[node];
    int e_end = offs[node + 1];
    float2 acc = hp2[(long)node * 64 + lane];  // self-loop contribution
    int e = s;
    for (; e + 4 <= e_end; e += 4) {
        int s0 = csr_src[e];
        int s1 = csr_src[e + 1];
        int s2 = csr_src[e + 2];
        int s3 = csr_src[e + 3];
        float2 v0 = hp2[(long)s0 * 64 + lane];
        float2 v1 = hp2[(long)s1 * 64 + lane];
        float2 v2 = hp2[(long)s2 * 64 + lane];
        float2 v3 = hp2[(long)s3 * 64 + lane];
        acc.x += (v0.x + v1.x) + (v2.x + v3.x);
        acc.y += (v0.y + v1.y) + (v2.y + v3.y);
    }
    for (; e < e_end; ++e) {
        int s0 = csr_src[e];
        float2 v0 = hp2[(long)s0 * 64 + lane];
        acc.x += v0.x;
        acc.y += v0.y;
    }
    float dv = dinv[node];
    float2 b = ((const float2*)bias)[lane];
    float2 o;
    o.x = fmaxf(fmaf(dv, acc.x, b.x), 0.0f);
    o.y = fmaxf(fmaf(dv, acc.y, b.y), 0.0f);
    ((float2*)out)[(long)node * 64 + lane] = o;
}

// ---------------- pooling: 2048 waves over sorted batch, boundary-flush atomics ----------------
__global__ __launch_bounds__(256) void pool2_k(const float* __restrict__ h, const int* __restrict__ batch,
                                               float* __restrict__ gsum) {
    int wave = (blockIdx.x * 256 + threadIdx.x) >> 6;
    int lane = threadIdx.x & 63;
    const int per = (NN + POOL_WAVES - 1) / POOL_WAVES;  // 49
    int s = wave * per;
    int e = min(s + per, NN);
    if (s >= e) return;
    const float2* h2 = (const float2*)h;
    float2 acc = {0.0f, 0.0f};
    int cur = batch[s];
    for (int r = s; r < e; ++r) {
        int b = batch[r];
        if (b != cur) {
            atomicAdd(&gsum[cur * DD + 2 * lane], acc.x);
            atomicAdd(&gsum[cur * DD + 2 * lane + 1], acc.y);
            acc.x = 0.0f; acc.y = 0.0f;
            cur = b;
        }
        float2 v = h2[(long)r * 64 + lane];
        acc.x += v.x;
        acc.y += v.y;
    }
    atomicAdd(&gsum[cur * DD + 2 * lane], acc.x);
    atomicAdd(&gsum[cur * DD + 2 * lane + 1], acc.y);
}

// ---------------- graph boundaries (batch sorted) ----------------
__global__ __launch_bounds__(256) void starts_k(const int* __restrict__ batch, int* __restrict__ starts) {
    int g = threadIdx.x;
    if (g > NG) return;
    if (g == NG) {
        starts[NG] = NN;
        return;
    }
    int lo = 0, hi = NN;
    while (lo < hi) {
        int mid = (lo + hi) >> 1;
        if (batch[mid] < g) lo = mid + 1;
        else hi = mid;
    }
    starts[g] = lo;
}

__global__ __launch_bounds__(256) void final_k(const float* __restrict__ gsum, const int* __restrict__ starts,
                                               const float* __restrict__ Wlin, const float* __restrict__ blin,
                                               float* __restrict__ out) {
    int idx = blockIdx.x * 256 + threadIdx.x;
    if (idx >= NG * NC) return;
    int g = idx / NC, c = idx % NC;
    int cnt = starts[g + 1] - starts[g];
    float inv = 1.0f / fmaxf((float)cnt, 1.0f);
    float acc = blin[c];
    for (int k = 0; k < DD; ++k) acc = fmaf(gsum[g * DD + k] * inv, Wlin[k * NC + c], acc);
    out[idx] = acc;
}

extern "C" void kernel_launch(void* const* d_in, const int* in_sizes, int n_in,
                              void* d_out, int out_size, void* d_ws, size_t ws_size,
                              hipStream_t stream) {
    const float* x     = (const float*)d_in[0];
    const int*   ei    = (const int*)d_in[1];   // [2][NE]: row=src, col=dst
    const int*   batch = (const int*)d_in[2];
    const float* W1    = (const float*)d_in[3];
    const float* b1    = (const float*)d_in[4];
    const float* W2    = (const float*)d_in[5];
    const float* b2    = (const float*)d_in[6];
    const float* Wlin  = (const float*)d_in[7];
    const float* blin  = (const float*)d_in[8];
    float* out = (float*)d_out;

    const int* erow = ei;
    const int* ecol = ei + NE;

    char* ws = (char*)d_ws;
    size_t off = 0;
    auto alloc = [&](size_t bytes) {
        void* p = ws + off;
        off = (off + bytes + 255) & ~(size_t)255;
        return p;
    };
    float* bufA     = (float*)alloc((size_t)NN * DD * 4);  // h' (scaled transform)
    float* bufB     = (float*)alloc((size_t)NN * DD * 4);  // layer output
    float* dinv     = (float*)alloc(NN * 4);
    int*   degi     = (int*)alloc(NN * 4);
    int*   offs     = (int*)alloc((NN + 1) * 4);
    int*   hist     = (int*)alloc((size_t)NB1 * NWG1 * 4);
    int*   tmpe     = (int*)alloc((size_t)NE * 4);
    int*   csrsrc   = (int*)alloc((size_t)NE * 4);
    int*   partials = (int*)alloc(NSCAN * 4);
    int*   psc      = (int*)alloc((NSCAN + 1) * 4);
    float* gsum     = (float*)alloc(NG * DD * 4);
    int*   starts   = (int*)alloc((NG + 1) * 4);
    (void)ws_size;

    hipMemsetAsync(degi, 0, NN * 4, stream);
    hipMemsetAsync(gsum, 0, NG * DD * 4, stream);

    deg_k<<<(NE + 255) / 256, 256, 0, stream>>>(ecol, degi);
    dinv_k<<<(NN + 255) / 256, 256, 0, stream>>>(degi, dinv);
    scan1_k<<<NSCAN, 256, 0, stream>>>(degi, offs, partials);
    scan2_k<<<1, 128, 0, stream>>>(partials, psc);
    scan3_k<<<(NN + 255) / 256, 256, 0, stream>>>(offs, psc);

    hist_k<<<NWG1, 256, 0, stream>>>(ecol, hist);
    histscan_k<<<NB1, 256, 0, stream>>>(offs, hist);
    part1_k<<<NWG1, 256, 0, stream>>>(erow, ecol, hist, tmpe);
    part2_k<<<NB1, 512, 0, stream>>>(offs, tmpe, csrsrc);

    // layer 1: x -> bufA (scaled transform) -> bufB (aggregated + relu)
    gemm_scaled_k<<<NN / 32, 256, 0, stream>>>(x, W1, dinv, bufA);
    agg_k<<<(NN + 3) / 4, 256, 0, stream>>>(bufA, dinv, offs, csrsrc, b1, bufB);
    // layer 2: bufB -> bufA -> bufB
    gemm_scaled_k<<<NN / 32, 256, 0, stream>>>(bufB, W2, dinv, bufA);
    agg_k<<<(NN + 3) / 4, 256, 0, stream>>>(bufA, dinv, offs, csrsrc, b2, bufB);

    // pooling + head
    starts_k<<<1, 256, 0, stream>>>(batch, starts);
    pool2_k<<<POOL_WAVES / 4, 256, 0, stream>>>(bufB, batch, gsum);
    final_k<<<(NG * NC + 255) / 256, 256, 0, stream>>>(gsum, starts, Wlin, blin, out);
}

// Round 8
// 435.849 us; speedup vs baseline: 7.4853x; 1.1864x over previous
//
#include <hip/hip_runtime.h>

#define NN 100000
#define NE 1600000
#define DD 128
#define NG 128
#define NC 10
#define SCAN_ELEMS 1024
#define NSCAN ((NN + SCAN_ELEMS - 1) / SCAN_ELEMS)  // 98
#define POOL_WAVES 2048

#define B1SH 8                        // coarse bucket = 256 nodes
#define NB1 ((NN + 255) / 256)        // 391 buckets
#define EPB 8192                      // edges per partition block
#define NWG1 ((NE + EPB - 1) / EPB)   // 196 partition blocks

// fp32 -> bf16 round-to-nearest-even
__device__ __forceinline__ unsigned short f2bf(float f) {
    unsigned int u = __float_as_uint(f);
    u = (u + 0x7fffu + ((u >> 16) & 1u)) >> 16;
    return (unsigned short)u;
}

// ---------------- degree histogram ----------------
__global__ __launch_bounds__(256) void deg_k(const int* __restrict__ col, int* __restrict__ degi) {
    int e = blockIdx.x * 256 + threadIdx.x;
    if (e < NE) atomicAdd(&degi[col[e]], 1);
}

__global__ __launch_bounds__(256) void dinv_k(const int* __restrict__ degi, float* __restrict__ dinv) {
    int i = blockIdx.x * 256 + threadIdx.x;
    if (i < NN) dinv[i] = rsqrtf((float)degi[i] + 1.0f);  // +1 self-loop
}

// ---------------- exclusive scan of degi -> offs ----------------
__global__ __launch_bounds__(256) void scan1_k(const int* __restrict__ degi, int* __restrict__ offs,
                                               int* __restrict__ partials) {
    __shared__ int tmp[256];
    int tid = threadIdx.x;
    int base = blockIdx.x * SCAN_ELEMS + tid * 4;
    int v[4];
    int s = 0;
#pragma unroll
    for (int j = 0; j < 4; ++j) {
        int idx = base + j;
        v[j] = (idx < NN) ? degi[idx] : 0;
        s += v[j];
    }
    tmp[tid] = s;
    __syncthreads();
    for (int off = 1; off < 256; off <<= 1) {
        int t = (tid >= off) ? tmp[tid - off] : 0;
        __syncthreads();
        tmp[tid] += t;
        __syncthreads();
    }
    int excl = tmp[tid] - s;
    int run = excl;
#pragma unroll
    for (int j = 0; j < 4; ++j) {
        int idx = base + j;
        if (idx < NN) offs[idx] = run;
        run += v[j];
    }
    if (tid == 255) partials[blockIdx.x] = tmp[255];
}

__global__ __launch_bounds__(128) void scan2_k(const int* __restrict__ partials, int* __restrict__ psc) {
    __shared__ int tmp[128];
    int tid = threadIdx.x;
    int v = (tid < NSCAN) ? partials[tid] : 0;
    tmp[tid] = v;
    __syncthreads();
    for (int off = 1; off < 128; off <<= 1) {
        int t = (tid >= off) ? tmp[tid - off] : 0;
        __syncthreads();
        tmp[tid] += t;
        __syncthreads();
    }
    int excl = tmp[tid] - v;
    if (tid < NSCAN) psc[tid] = excl;
    if (tid == 127) psc[NSCAN] = tmp[127];  // total (== NE)
}

__global__ __launch_bounds__(256) void scan3_k(int* __restrict__ offs, const int* __restrict__ psc) {
    int i = blockIdx.x * 256 + threadIdx.x;
    if (i < NN) {
        offs[i] += psc[i >> 10];
        if (i == 0) offs[NN] = psc[NSCAN];
    }
}

// ---------------- radix partition P1a: per-(wg,bucket) histogram ----------------
__global__ __launch_bounds__(256) void hist_k(const int* __restrict__ col, int* __restrict__ hist) {
    __shared__ int lh[NB1];
    int t = threadIdx.x, w = blockIdx.x;
    for (int i = t; i < NB1; i += 256) lh[i] = 0;
    __syncthreads();
    int base = w * EPB;
    int lim = min(base + EPB, NE);
#pragma unroll 4
    for (int e = base + t; e < lim; e += 256) atomicAdd(&lh[col[e] >> B1SH], 1);
    __syncthreads();
    for (int i = t; i < NB1; i += 256) hist[i * NWG1 + w] = lh[i];
}

// ---------------- P1b: per-bucket exclusive scan over wgs, seeded by offs[b*256] ----------------
__global__ __launch_bounds__(256) void histscan_k(const int* __restrict__ offs, int* __restrict__ hist) {
    __shared__ int tmp[256];
    int b = blockIdx.x, t = threadIdx.x;
    int v = (t < NWG1) ? hist[b * NWG1 + t] : 0;
    tmp[t] = v;
    __syncthreads();
    for (int o = 1; o < 256; o <<= 1) {
        int u = (t >= o) ? tmp[t - o] : 0;
        __syncthreads();
        tmp[t] += u;
        __syncthreads();
    }
    int excl = tmp[t] - v;
    if (t < NWG1) hist[b * NWG1 + t] = offs[b << B1SH] + excl;
}

// ---------------- P1c: partition edges into coarse-bucket segments (packed) ----------------
__global__ __launch_bounds__(256) void part1_k(const int* __restrict__ row, const int* __restrict__ col,
                                               const int* __restrict__ hist, int* __restrict__ tmpe) {
    __shared__ int lcur[NB1];
    int t = threadIdx.x, w = blockIdx.x;
    for (int i = t; i < NB1; i += 256) lcur[i] = hist[i * NWG1 + w];
    __syncthreads();
    int base = w * EPB;
    int lim = min(base + EPB, NE);
#pragma unroll 4
    for (int e = base + t; e < lim; e += 256) {
        int c = col[e];
        int pos = atomicAdd(&lcur[c >> B1SH], 1);
        tmpe[pos] = (row[e] << B1SH) | (c & 255);  // src<2^17 -> 25 bits
    }
}

// ---------------- P2: within-bucket scatter to exact per-node CSR ----------------
__global__ __launch_bounds__(512) void part2_k(const int* __restrict__ offs, const int* __restrict__ tmpe,
                                               int* __restrict__ csr_src) {
    __shared__ int lcur[256];
    int b = blockIdx.x, t = threadIdx.x;
    int n0 = b << B1SH;
    for (int i = t; i < 256; i += 512) {
        int node = n0 + i;
        lcur[i] = (node < NN) ? offs[node] : 0;
    }
    __syncthreads();
    int ebeg = offs[n0];
    int eend = offs[min(n0 + 256, NN)];
#pragma unroll 4
    for (int e = ebeg + t; e < eend; e += 512) {
        int p = tmpe[e];
        int pos = atomicAdd(&lcur[p & 255], 1);
        csr_src[pos] = p >> B1SH;
    }
}

// ---------------- GEMM: outb[r][:] = bf16( dinv[r] * (X[r][:] @ W) )  (128x128 W) ----------------
__global__ __launch_bounds__(256) void gemm_scaled_k(const float* __restrict__ X,
                                                     const float* __restrict__ W,
                                                     const float* __restrict__ dinv,
                                                     unsigned short* __restrict__ outb) {
    __shared__ float xs[32 * 130];
    int tid = threadIdx.x;
    long base = (long)blockIdx.x * 32 * DD;
#pragma unroll
    for (int i = 0; i < 16; ++i) {
        int idx = tid + i * 256;
        int r = idx >> 7, k = idx & 127;
        xs[r * 130 + k] = X[base + idx];
    }
    __syncthreads();
    int cg = tid & 31;   // cols 4cg..4cg+3
    int rg = tid >> 5;   // rows 4rg..4rg+3
    const float4* W4 = (const float4*)W;
    float4 a0 = {0, 0, 0, 0}, a1 = {0, 0, 0, 0}, a2 = {0, 0, 0, 0}, a3 = {0, 0, 0, 0};
    const float* x0p = xs + (4 * rg + 0) * 130;
    const float* x1p = xs + (4 * rg + 1) * 130;
    const float* x2p = xs + (4 * rg + 2) * 130;
    const float* x3p = xs + (4 * rg + 3) * 130;
#pragma unroll 8
    for (int k = 0; k < DD; ++k) {
        float4 w = W4[k * 32 + cg];
        float x0 = x0p[k], x1 = x1p[k], x2 = x2p[k], x3 = x3p[k];
        a0.x = fmaf(x0, w.x, a0.x); a0.y = fmaf(x0, w.y, a0.y);
        a0.z = fmaf(x0, w.z, a0.z); a0.w = fmaf(x0, w.w, a0.w);
        a1.x = fmaf(x1, w.x, a1.x); a1.y = fmaf(x1, w.y, a1.y);
        a1.z = fmaf(x1, w.z, a1.z); a1.w = fmaf(x1, w.w, a1.w);
        a2.x = fmaf(x2, w.x, a2.x); a2.y = fmaf(x2, w.y, a2.y);
        a2.z = fmaf(x2, w.z, a2.z); a2.w = fmaf(x2, w.w, a2.w);
        a3.x = fmaf(x3, w.x, a3.x); a3.y = fmaf(x3, w.y, a3.y);
        a3.z = fmaf(x3, w.z, a3.z); a3.w = fmaf(x3, w.w, a3.w);
    }
    int row = blockIdx.x * 32 + 4 * rg;
    ushort4 pk;
    float d;
    d = dinv[row + 0];
    pk = make_ushort4(f2bf(d * a0.x), f2bf(d * a0.y), f2bf(d * a0.z), f2bf(d * a0.w));
    ((ushort4*)(outb + (long)(row + 0) * DD))[cg] = pk;
    d = dinv[row + 1];
    pk = make_ushort4(f2bf(d * a1.x), f2bf(d * a1.y), f2bf(d * a1.z), f2bf(d * a1.w));
    ((ushort4*)(outb + (long)(row + 1) * DD))[cg] = pk;
    d = dinv[row + 2];
    pk = make_ushort4(f2bf(d * a2.x), f2bf(d * a2.y), f2bf(d * a2.z), f2bf(d * a2.w));
    ((ushort4*)(outb + (long)(row + 2) * DD))[cg] = pk;
    d = dinv[row + 3];
    pk = make_ushort4(f2bf(d * a3.x), f2bf(d * a3.y), f2bf(d * a3.z), f2bf(d * a3.w));
    ((ushort4*)(outb + (long)(row + 3) * DD))[cg] = pk;
}

// ---------------- aggregation: wave per node, bf16 gather, fp32 accumulate ----------------
__global__ __launch_bounds__(256) void agg_k(const unsigned short* __restrict__ hpb_,
                                             const float* __restrict__ dinv,
                                             const int* __restrict__ offs, const int* __restrict__ csr_src,
                                             const float* __restrict__ bias, float* __restrict__ out) {
    int node = (blockIdx.x << 2) + (threadIdx.x >> 6);
    if (node >= NN) return;
    int lane = threadIdx.x & 63;
    const unsigned int* hpb = (const unsigned int*)hpb_;  // 2 bf16 per uint
    int s = offs[node];
    int e_end = offs[node + 1];
    unsigned int ps = hpb[(long)node * 64 + lane];  // self-loop
    float accx = __uint_as_float(ps << 16);
    float accy = __uint_as_float(ps & 0xffff0000u);
    int e = s;
    for (; e + 4 <= e_end; e += 4) {
        int s0 = csr_src[e];
        int s1 = csr_src[e + 1];
        int s2 = csr_src[e + 2];
        int s3 = csr_src[e + 3];
        unsigned int p0 = hpb[(long)s0 * 64 + lane];
        unsigned int p1 = hpb[(long)s1 * 64 + lane];
        unsigned int p2 = hpb[(long)s2 * 64 + lane];
        unsigned int p3 = hpb[(long)s3 * 64 + lane];
        accx += __uint_as_float(p0 << 16) + __uint_as_float(p1 << 16);
        accx += __uint_as_float(p2 << 16) + __uint_as_float(p3 << 16);
        accy += __uint_as_float(p0 & 0xffff0000u) + __uint_as_float(p1 & 0xffff0000u);
        accy += __uint_as_float(p2 & 0xffff0000u) + __uint_as_float(p3 & 0xffff0000u);
    }
    for (; e < e_end; ++e) {
        unsigned int p0 = hpb[(long)csr_src[e] * 64 + lane];
        accx += __uint_as_float(p0 << 16);
        accy += __uint_as_float(p0 & 0xffff0000u);
    }
    float dv = dinv[node];
    float2 b = ((const float2*)bias)[lane];
    float2 o;
    o.x = fmaxf(fmaf(dv, accx, b.x), 0.0f);
    o.y = fmaxf(fmaf(dv, accy, b.y), 0.0f);
    ((float2*)out)[(long)node * 64 + lane] = o;
}

// ---------------- pooling: 2048 waves over sorted batch, boundary-flush atomics ----------------
__global__ __launch_bounds__(256) void pool2_k(const float* __restrict__ h, const int* __restrict__ batch,
                                               float* __restrict__ gsum) {
    int wave = (blockIdx.x * 256 + threadIdx.x) >> 6;
    int lane = threadIdx.x & 63;
    const int per = (NN + POOL_WAVES - 1) / POOL_WAVES;  // 49
    int s = wave * per;
    int e = min(s + per, NN);
    if (s >= e) return;
    const float2* h2 = (const float2*)h;
    float2 acc = {0.0f, 0.0f};
    int cur = batch[s];
    for (int r = s; r < e; ++r) {
        int b = batch[r];
        if (b != cur) {
            atomicAdd(&gsum[cur * DD + 2 * lane], acc.x);
            atomicAdd(&gsum[cur * DD + 2 * lane + 1], acc.y);
            acc.x = 0.0f; acc.y = 0.0f;
            cur = b;
        }
        float2 v = h2[(long)r * 64 + lane];
        acc.x += v.x;
        acc.y += v.y;
    }
    atomicAdd(&gsum[cur * DD + 2 * lane], acc.x);
    atomicAdd(&gsum[cur * DD + 2 * lane + 1], acc.y);
}

// ---------------- graph boundaries (batch sorted) ----------------
__global__ __launch_bounds__(256) void starts_k(const int* __restrict__ batch, int* __restrict__ starts) {
    int g = threadIdx.x;
    if (g > NG) return;
    if (g == NG) {
        starts[NG] = NN;
        return;
    }
    int lo = 0, hi = NN;
    while (lo < hi) {
        int mid = (lo + hi) >> 1;
        if (batch[mid] < g) lo = mid + 1;
        else hi = mid;
    }
    starts[g] = lo;
}

__global__ __launch_bounds__(256) void final_k(const float* __restrict__ gsum, const int* __restrict__ starts,
                                               const float* __restrict__ Wlin, const float* __restrict__ blin,
                                               float* __restrict__ out) {
    int idx = blockIdx.x * 256 + threadIdx.x;
    if (idx >= NG * NC) return;
    int g = idx / NC, c = idx % NC;
    int cnt = starts[g + 1] - starts[g];
    float inv = 1.0f / fmaxf((float)cnt, 1.0f);
    float acc = blin[c];
    for (int k = 0; k < DD; ++k) acc = fmaf(gsum[g * DD + k] * inv, Wlin[k * NC + c], acc);
    out[idx] = acc;
}

extern "C" void kernel_launch(void* const* d_in, const int* in_sizes, int n_in,
                              void* d_out, int out_size, void* d_ws, size_t ws_size,
                              hipStream_t stream) {
    const float* x     = (const float*)d_in[0];
    const int*   ei    = (const int*)d_in[1];   // [2][NE]: row=src, col=dst
    const int*   batch = (const int*)d_in[2];
    const float* W1    = (const float*)d_in[3];
    const float* b1    = (const float*)d_in[4];
    const float* W2    = (const float*)d_in[5];
    const float* b2    = (const float*)d_in[6];
    const float* Wlin  = (const float*)d_in[7];
    const float* blin  = (const float*)d_in[8];
    float* out = (float*)d_out;

    const int* erow = ei;
    const int* ecol = ei + NE;

    char* ws = (char*)d_ws;
    size_t off = 0;
    auto alloc = [&](size_t bytes) {
        void* p = ws + off;
        off = (off + bytes + 255) & ~(size_t)255;
        return p;
    };
    float*          bufB   = (float*)alloc((size_t)NN * DD * 4);  // agg output (fp32)
    unsigned short* hbuf   = (unsigned short*)alloc((size_t)NN * DD * 2);  // h' (bf16)
    float* dinv     = (float*)alloc(NN * 4);
    int*   degi     = (int*)alloc(NN * 4);
    int*   offs     = (int*)alloc((NN + 1) * 4);
    int*   hist     = (int*)alloc((size_t)NB1 * NWG1 * 4);
    int*   tmpe     = (int*)alloc((size_t)NE * 4);
    int*   csrsrc   = (int*)alloc((size_t)NE * 4);
    int*   partials = (int*)alloc(NSCAN * 4);
    int*   psc      = (int*)alloc((NSCAN + 1) * 4);
    float* gsum     = (float*)alloc(NG * DD * 4);
    int*   starts   = (int*)alloc((NG + 1) * 4);
    (void)ws_size;

    hipMemsetAsync(degi, 0, NN * 4, stream);
    hipMemsetAsync(gsum, 0, NG * DD * 4, stream);

    deg_k<<<(NE + 255) / 256, 256, 0, stream>>>(ecol, degi);
    dinv_k<<<(NN + 255) / 256, 256, 0, stream>>>(degi, dinv);
    scan1_k<<<NSCAN, 256, 0, stream>>>(degi, offs, partials);
    scan2_k<<<1, 128, 0, stream>>>(partials, psc);
    scan3_k<<<(NN + 255) / 256, 256, 0, stream>>>(offs, psc);

    hist_k<<<NWG1, 256, 0, stream>>>(ecol, hist);
    histscan_k<<<NB1, 256, 0, stream>>>(offs, hist);
    part1_k<<<NWG1, 256, 0, stream>>>(erow, ecol, hist, tmpe);
    part2_k<<<NB1, 512, 0, stream>>>(offs, tmpe, csrsrc);

    // layer 1: x -> hbuf (bf16 scaled transform) -> bufB (fp32 aggregated + relu)
    gemm_scaled_k<<<NN / 32, 256, 0, stream>>>(x, W1, dinv, hbuf);
    agg_k<<<(NN + 3) / 4, 256, 0, stream>>>(hbuf, dinv, offs, csrsrc, b1, bufB);
    // layer 2: bufB -> hbuf -> bufB
    gemm_scaled_k<<<NN / 32, 256, 0, stream>>>(bufB, W2, dinv, hbuf);
    agg_k<<<(NN + 3) / 4, 256, 0, stream>>>(hbuf, dinv, offs, csrsrc, b2, bufB);

    // pooling + head
    starts_k<<<1, 256, 0, stream>>>(batch, starts);
    pool2_k<<<POOL_WAVES / 4, 256, 0, stream>>>(bufB, batch, gsum);
    final_k<<<(NG * NC + 255) / 256, 256, 0, stream>>>(gsum, starts, Wlin, blin, out);
}

// Round 9
// 360.886 us; speedup vs baseline: 9.0402x; 1.2077x over previous
//
#include <hip/hip_runtime.h>

#define NN 100000
#define NE 1600000
#define DD 128
#define NG 128
#define NC 10
#define SCAN_ELEMS 1024
#define NSCAN ((NN + SCAN_ELEMS - 1) / SCAN_ELEMS)  // 98
#define POOL_WAVES 2048

#define B1SH 8                        // coarse bucket = 256 nodes
#define NB1 ((NN + 255) / 256)        // 391 buckets
#define EPB 8192                      // edges per partition block
#define NWG1 ((NE + EPB - 1) / EPB)   // 196 partition blocks

typedef __attribute__((ext_vector_type(8))) short short8v;   // 8 bf16 (4 VGPRs)
typedef __attribute__((ext_vector_type(4))) float f32x4;     // MFMA acc

// fp32 -> bf16 round-to-nearest-even
__device__ __forceinline__ unsigned short f2bf(float f) {
    unsigned int u = __float_as_uint(f);
    u = (u + 0x7fffu + ((u >> 16) & 1u)) >> 16;
    return (unsigned short)u;
}

// ---------------- degree histogram ----------------
__global__ __launch_bounds__(256) void deg_k(const int* __restrict__ col, int* __restrict__ degi) {
    int e = blockIdx.x * 256 + threadIdx.x;
    if (e < NE) atomicAdd(&degi[col[e]], 1);
}

__global__ __launch_bounds__(256) void dinv_k(const int* __restrict__ degi, float* __restrict__ dinv) {
    int i = blockIdx.x * 256 + threadIdx.x;
    if (i < NN) dinv[i] = rsqrtf((float)degi[i] + 1.0f);  // +1 self-loop
}

// ---------------- exclusive scan of degi -> offs ----------------
__global__ __launch_bounds__(256) void scan1_k(const int* __restrict__ degi, int* __restrict__ offs,
                                               int* __restrict__ partials) {
    __shared__ int tmp[256];
    int tid = threadIdx.x;
    int base = blockIdx.x * SCAN_ELEMS + tid * 4;
    int v[4];
    int s = 0;
#pragma unroll
    for (int j = 0; j < 4; ++j) {
        int idx = base + j;
        v[j] = (idx < NN) ? degi[idx] : 0;
        s += v[j];
    }
    tmp[tid] = s;
    __syncthreads();
    for (int off = 1; off < 256; off <<= 1) {
        int t = (tid >= off) ? tmp[tid - off] : 0;
        __syncthreads();
        tmp[tid] += t;
        __syncthreads();
    }
    int excl = tmp[tid] - s;
    int run = excl;
#pragma unroll
    for (int j = 0; j < 4; ++j) {
        int idx = base + j;
        if (idx < NN) offs[idx] = run;
        run += v[j];
    }
    if (tid == 255) partials[blockIdx.x] = tmp[255];
}

__global__ __launch_bounds__(128) void scan2_k(const int* __restrict__ partials, int* __restrict__ psc) {
    __shared__ int tmp[128];
    int tid = threadIdx.x;
    int v = (tid < NSCAN) ? partials[tid] : 0;
    tmp[tid] = v;
    __syncthreads();
    for (int off = 1; off < 128; off <<= 1) {
        int t = (tid >= off) ? tmp[tid - off] : 0;
        __syncthreads();
        tmp[tid] += t;
        __syncthreads();
    }
    int excl = tmp[tid] - v;
    if (tid < NSCAN) psc[tid] = excl;
    if (tid == 127) psc[NSCAN] = tmp[127];  // total (== NE)
}

__global__ __launch_bounds__(256) void scan3_k(int* __restrict__ offs, const int* __restrict__ psc) {
    int i = blockIdx.x * 256 + threadIdx.x;
    if (i < NN) {
        offs[i] += psc[i >> 10];
        if (i == 0) offs[NN] = psc[NSCAN];
    }
}

// ---------------- radix partition P1a: per-(wg,bucket) histogram ----------------
__global__ __launch_bounds__(256) void hist_k(const int* __restrict__ col, int* __restrict__ hist) {
    __shared__ int lh[NB1];
    int t = threadIdx.x, w = blockIdx.x;
    for (int i = t; i < NB1; i += 256) lh[i] = 0;
    __syncthreads();
    int base = w * EPB;
    int lim = min(base + EPB, NE);
#pragma unroll 4
    for (int e = base + t; e < lim; e += 256) atomicAdd(&lh[col[e] >> B1SH], 1);
    __syncthreads();
    for (int i = t; i < NB1; i += 256) hist[i * NWG1 + w] = lh[i];
}

// ---------------- P1b: per-bucket exclusive scan over wgs, seeded by offs[b*256] ----------------
__global__ __launch_bounds__(256) void histscan_k(const int* __restrict__ offs, int* __restrict__ hist) {
    __shared__ int tmp[256];
    int b = blockIdx.x, t = threadIdx.x;
    int v = (t < NWG1) ? hist[b * NWG1 + t] : 0;
    tmp[t] = v;
    __syncthreads();
    for (int o = 1; o < 256; o <<= 1) {
        int u = (t >= o) ? tmp[t - o] : 0;
        __syncthreads();
        tmp[t] += u;
        __syncthreads();
    }
    int excl = tmp[t] - v;
    if (t < NWG1) hist[b * NWG1 + t] = offs[b << B1SH] + excl;
}

// ---------------- P1c: partition edges into coarse-bucket segments (packed) ----------------
__global__ __launch_bounds__(256) void part1_k(const int* __restrict__ row, const int* __restrict__ col,
                                               const int* __restrict__ hist, int* __restrict__ tmpe) {
    __shared__ int lcur[NB1];
    int t = threadIdx.x, w = blockIdx.x;
    for (int i = t; i < NB1; i += 256) lcur[i] = hist[i * NWG1 + w];
    __syncthreads();
    int base = w * EPB;
    int lim = min(base + EPB, NE);
#pragma unroll 4
    for (int e = base + t; e < lim; e += 256) {
        int c = col[e];
        int pos = atomicAdd(&lcur[c >> B1SH], 1);
        tmpe[pos] = (row[e] << B1SH) | (c & 255);  // src<2^17 -> 25 bits
    }
}

// ---------------- P2: within-bucket scatter to exact per-node CSR ----------------
__global__ __launch_bounds__(512) void part2_k(const int* __restrict__ offs, const int* __restrict__ tmpe,
                                               int* __restrict__ csr_src) {
    __shared__ int lcur[256];
    int b = blockIdx.x, t = threadIdx.x;
    int n0 = b << B1SH;
    for (int i = t; i < 256; i += 512) {
        int node = n0 + i;
        lcur[i] = (node < NN) ? offs[node] : 0;
    }
    __syncthreads();
    int ebeg = offs[n0];
    int eend = offs[min(n0 + 256, NN)];
#pragma unroll 4
    for (int e = ebeg + t; e < eend; e += 512) {
        int p = tmpe[e];
        int pos = atomicAdd(&lcur[p & 255], 1);
        csr_src[pos] = p >> B1SH;
    }
}

// ---------------- W pack: fp32 [K=128][N=128] -> bf16 MFMA B-fragment order ----------------
// frag(n, kk, lane, j): k = kk*32 + (lane>>4)*8 + j, col = n*16 + (lane&15)
__global__ __launch_bounds__(256) void pack_w_k(const float* __restrict__ W, unsigned short* __restrict__ Wpk) {
    int t = threadIdx.x;
    for (int f = t * 64; f < t * 64 + 64; ++f) {
        int j = f & 7, lane = (f >> 3) & 63, kk = (f >> 9) & 3, n = f >> 11;
        int k = kk * 32 + ((lane >> 4) << 3) + j;
        int c = n * 16 + (lane & 15);
        Wpk[f] = f2bf(W[k * DD + c]);
    }
}

// ---------------- MFMA GEMM: outb[r][:] = bf16( dinv[r] * (X[r][:] @ W) ) ----------------
// block = 64 rows (4 waves x 16 rows); W staged in LDS as packed frags.
template <int IN_BF16>
__global__ __launch_bounds__(256) void gemm_mfma_k(const void* __restrict__ Xv,
                                                   const unsigned short* __restrict__ Wpk,
                                                   const float* __restrict__ dinv,
                                                   unsigned short* __restrict__ outb) {
    __shared__ unsigned short wlds[16384];  // 32 KB
    int tid = threadIdx.x;
    const uint4* wg = (const uint4*)Wpk;
    uint4* wl = (uint4*)wlds;
#pragma unroll
    for (int i = 0; i < 8; ++i) wl[tid + i * 256] = wg[tid + i * 256];
    __syncthreads();

    int w = tid >> 6, lane = tid & 63;
    int kg = lane >> 4;  // 0..3
    int rowbase = blockIdx.x * 64 + w * 16;
    int rl = min(rowbase + (lane & 15), NN - 1);

    short8v a[4];
    if (IN_BF16) {
        const unsigned short* xb = (const unsigned short*)Xv;
#pragma unroll
        for (int kk = 0; kk < 4; ++kk)
            a[kk] = *(const short8v*)(xb + (long)rl * DD + kk * 32 + kg * 8);
    } else {
        const float* xf = (const float*)Xv;
#pragma unroll
        for (int kk = 0; kk < 4; ++kk) {
            float4 f0 = *(const float4*)(xf + (long)rl * DD + kk * 32 + kg * 8);
            float4 f1 = *(const float4*)(xf + (long)rl * DD + kk * 32 + kg * 8 + 4);
            short8v t;
            t[0] = (short)f2bf(f0.x); t[1] = (short)f2bf(f0.y);
            t[2] = (short)f2bf(f0.z); t[3] = (short)f2bf(f0.w);
            t[4] = (short)f2bf(f1.x); t[5] = (short)f2bf(f1.y);
            t[6] = (short)f2bf(f1.z); t[7] = (short)f2bf(f1.w);
            a[kk] = t;
        }
    }

    f32x4 acc[8];
#pragma unroll
    for (int n = 0; n < 8; ++n) acc[n] = (f32x4){0.f, 0.f, 0.f, 0.f};
#pragma unroll
    for (int n = 0; n < 8; ++n) {
#pragma unroll
        for (int kk = 0; kk < 4; ++kk) {
            short8v b = *(const short8v*)(wlds + ((n * 4 + kk) * 64 + lane) * 8);
            acc[n] = __builtin_amdgcn_mfma_f32_16x16x32_bf16(a[kk], b, acc[n], 0, 0, 0);
        }
    }

    // D: col = n*16 + (lane&15), row = rowbase + kg*4 + reg
    int c0 = lane & 15;
#pragma unroll
    for (int reg = 0; reg < 4; ++reg) {
        int row = rowbase + kg * 4 + reg;
        if (row < NN) {
            float dv = dinv[row];
            unsigned short* op = outb + (long)row * DD + c0;
#pragma unroll
            for (int n = 0; n < 8; ++n) op[n * 16] = f2bf(dv * acc[n][reg]);
        }
    }
}

// ---------------- aggregation: wave per node, bf16 gather, fp32 accumulate ----------------
// OUT_BF16=1 -> write bf16 (feeds next gemm); else fp32 (feeds pooling)
template <int OUT_BF16>
__global__ __launch_bounds__(256) void agg_k(const unsigned short* __restrict__ hpb_,
                                             const float* __restrict__ dinv,
                                             const int* __restrict__ offs, const int* __restrict__ csr_src,
                                             const float* __restrict__ bias, void* __restrict__ outv) {
    int node = (blockIdx.x << 2) + (threadIdx.x >> 6);
    if (node >= NN) return;
    int lane = threadIdx.x & 63;
    const unsigned int* hpb = (const unsigned int*)hpb_;  // 2 bf16 per uint
    int s = offs[node];
    int e_end = offs[node + 1];
    unsigned int ps = hpb[(long)node * 64 + lane];  // self-loop
    float accx = __uint_as_float(ps << 16);
    float accy = __uint_as_float(ps & 0xffff0000u);
    int e = s;
    for (; e + 4 <= e_end; e += 4) {
        int s0 = csr_src[e];
        int s1 = csr_src[e + 1];
        int s2 = csr_src[e + 2];
        int s3 = csr_src[e + 3];
        unsigned int p0 = hpb[(long)s0 * 64 + lane];
        unsigned int p1 = hpb[(long)s1 * 64 + lane];
        unsigned int p2 = hpb[(long)s2 * 64 + lane];
        unsigned int p3 = hpb[(long)s3 * 64 + lane];
        accx += __uint_as_float(p0 << 16) + __uint_as_float(p1 << 16);
        accx += __uint_as_float(p2 << 16) + __uint_as_float(p3 << 16);
        accy += __uint_as_float(p0 & 0xffff0000u) + __uint_as_float(p1 & 0xffff0000u);
        accy += __uint_as_float(p2 & 0xffff0000u) + __uint_as_float(p3 & 0xffff0000u);
    }
    for (; e < e_end; ++e) {
        unsigned int p0 = hpb[(long)csr_src[e] * 64 + lane];
        accx += __uint_as_float(p0 << 16);
        accy += __uint_as_float(p0 & 0xffff0000u);
    }
    float dv = dinv[node];
    float2 b = ((const float2*)bias)[lane];
    float ox = fmaxf(fmaf(dv, accx, b.x), 0.0f);
    float oy = fmaxf(fmaf(dv, accy, b.y), 0.0f);
    if (OUT_BF16) {
        ushort2 pk = make_ushort2(f2bf(ox), f2bf(oy));
        ((ushort2*)outv)[(long)node * 64 + lane] = pk;
    } else {
        ((float2*)outv)[(long)node * 64 + lane] = make_float2(ox, oy);
    }
}

// ---------------- pooling: 2048 waves over sorted batch, boundary-flush atomics ----------------
__global__ __launch_bounds__(256) void pool2_k(const float* __restrict__ h, const int* __restrict__ batch,
                                               float* __restrict__ gsum) {
    int wave = (blockIdx.x * 256 + threadIdx.x) >> 6;
    int lane = threadIdx.x & 63;
    const int per = (NN + POOL_WAVES - 1) / POOL_WAVES;  // 49
    int s = wave * per;
    int e = min(s + per, NN);
    if (s >= e) return;
    const float2* h2 = (const float2*)h;
    float2 acc = {0.0f, 0.0f};
    int cur = batch[s];
    for (int r = s; r < e; ++r) {
        int b = batch[r];
        if (b != cur) {
            atomicAdd(&gsum[cur * DD + 2 * lane], acc.x);
            atomicAdd(&gsum[cur * DD + 2 * lane + 1], acc.y);
            acc.x = 0.0f; acc.y = 0.0f;
            cur = b;
        }
        float2 v = h2[(long)r * 64 + lane];
        acc.x += v.x;
        acc.y += v.y;
    }
    atomicAdd(&gsum[cur * DD + 2 * lane], acc.x);
    atomicAdd(&gsum[cur * DD + 2 * lane + 1], acc.y);
}

// ---------------- graph boundaries (batch sorted) ----------------
__global__ __launch_bounds__(256) void starts_k(const int* __restrict__ batch, int* __restrict__ starts) {
    int g = threadIdx.x;
    if (g > NG) return;
    if (g == NG) {
        starts[NG] = NN;
        return;
    }
    int lo = 0, hi = NN;
    while (lo < hi) {
        int mid = (lo + hi) >> 1;
        if (batch[mid] < g) lo = mid + 1;
        else hi = mid;
    }
    starts[g] = lo;
}

__global__ __launch_bounds__(256) void final_k(const float* __restrict__ gsum, const int* __restrict__ starts,
                                               const float* __restrict__ Wlin, const float* __restrict__ blin,
                                               float* __restrict__ out) {
    int idx = blockIdx.x * 256 + threadIdx.x;
    if (idx >= NG * NC) return;
    int g = idx / NC, c = idx % NC;
    int cnt = starts[g + 1] - starts[g];
    float inv = 1.0f / fmaxf((float)cnt, 1.0f);
    float acc = blin[c];
    for (int k = 0; k < DD; ++k) acc = fmaf(gsum[g * DD + k] * inv, Wlin[k * NC + c], acc);
    out[idx] = acc;
}

extern "C" void kernel_launch(void* const* d_in, const int* in_sizes, int n_in,
                              void* d_out, int out_size, void* d_ws, size_t ws_size,
                              hipStream_t stream) {
    const float* x     = (const float*)d_in[0];
    const int*   ei    = (const int*)d_in[1];   // [2][NE]: row=src, col=dst
    const int*   batch = (const int*)d_in[2];
    const float* W1    = (const float*)d_in[3];
    const float* b1    = (const float*)d_in[4];
    const float* W2    = (const float*)d_in[5];
    const float* b2    = (const float*)d_in[6];
    const float* Wlin  = (const float*)d_in[7];
    const float* blin  = (const float*)d_in[8];
    float* out = (float*)d_out;

    const int* erow = ei;
    const int* ecol = ei + NE;

    char* ws = (char*)d_ws;
    size_t off = 0;
    auto alloc = [&](size_t bytes) {
        void* p = ws + off;
        off = (off + bytes + 255) & ~(size_t)255;
        return p;
    };
    float*          bufB  = (float*)alloc((size_t)NN * DD * 4);           // layer-2 agg out (fp32)
    unsigned short* hbuf  = (unsigned short*)alloc((size_t)NN * DD * 2);  // gemm out h' (bf16)
    unsigned short* habuf = (unsigned short*)alloc((size_t)NN * DD * 2);  // layer-1 agg out (bf16)
    unsigned short* Wpk1  = (unsigned short*)alloc(16384 * 2);
    unsigned short* Wpk2  = (unsigned short*)alloc(16384 * 2);
    float* dinv     = (float*)alloc(NN * 4);
    int*   degi     = (int*)alloc(NN * 4);
    int*   offs     = (int*)alloc((NN + 1) * 4);
    int*   hist     = (int*)alloc((size_t)NB1 * NWG1 * 4);
    int*   tmpe     = (int*)alloc((size_t)NE * 4);
    int*   csrsrc   = (int*)alloc((size_t)NE * 4);
    int*   partials = (int*)alloc(NSCAN * 4);
    int*   psc      = (int*)alloc((NSCAN + 1) * 4);
    float* gsum     = (float*)alloc(NG * DD * 4);
    int*   starts   = (int*)alloc((NG + 1) * 4);
    (void)ws_size;

    hipMemsetAsync(degi, 0, NN * 4, stream);
    hipMemsetAsync(gsum, 0, NG * DD * 4, stream);

    deg_k<<<(NE + 255) / 256, 256, 0, stream>>>(ecol, degi);
    dinv_k<<<(NN + 255) / 256, 256, 0, stream>>>(degi, dinv);
    scan1_k<<<NSCAN, 256, 0, stream>>>(degi, offs, partials);
    scan2_k<<<1, 128, 0, stream>>>(partials, psc);
    scan3_k<<<(NN + 255) / 256, 256, 0, stream>>>(offs, psc);

    hist_k<<<NWG1, 256, 0, stream>>>(ecol, hist);
    histscan_k<<<NB1, 256, 0, stream>>>(offs, hist);
    part1_k<<<NWG1, 256, 0, stream>>>(erow, ecol, hist, tmpe);
    part2_k<<<NB1, 512, 0, stream>>>(offs, tmpe, csrsrc);

    pack_w_k<<<1, 256, 0, stream>>>(W1, Wpk1);
    pack_w_k<<<1, 256, 0, stream>>>(W2, Wpk2);

    int gblocks = (NN + 63) / 64;  // 1563
    // layer 1: x (fp32) -> hbuf (bf16 h') -> habuf (bf16 agg+relu)
    gemm_mfma_k<0><<<gblocks, 256, 0, stream>>>(x, Wpk1, dinv, hbuf);
    agg_k<1><<<(NN + 3) / 4, 256, 0, stream>>>(hbuf, dinv, offs, csrsrc, b1, habuf);
    // layer 2: habuf (bf16) -> hbuf (bf16 h') -> bufB (fp32 agg+relu)
    gemm_mfma_k<1><<<gblocks, 256, 0, stream>>>(habuf, Wpk2, dinv, hbuf);
    agg_k<0><<<(NN + 3) / 4, 256, 0, stream>>>(hbuf, dinv, offs, csrsrc, b2, bufB);

    // pooling + head
    starts_k<<<1, 256, 0, stream>>>(batch, starts);
    pool2_k<<<POOL_WAVES / 4, 256, 0, stream>>>(bufB, batch, gsum);
    final_k<<<(NG * NC + 255) / 256, 256, 0, stream>>>(gsum, starts, Wlin, blin, out);
}

// Round 10
// 278.890 us; speedup vs baseline: 11.6981x; 1.2940x over previous
//
#include <hip/hip_runtime.h>

#define NN 100000
#define NE 1600000
#define DD 128
#define NG 128
#define NC 10
#define POOL_WAVES 2048

#define B1SH 8                        // coarse bucket = 256 nodes
#define NB1 ((NN + 255) / 256)        // 391 buckets
#define EPB 8192                      // edges per partition block
#define NWG1 ((NE + EPB - 1) / EPB)   // 196 partition blocks

typedef __attribute__((ext_vector_type(8))) short short8v;   // 8 bf16 (4 VGPRs)
typedef __attribute__((ext_vector_type(4))) float f32x4;     // MFMA acc

// fp32 -> bf16 round-to-nearest-even
__device__ __forceinline__ unsigned short f2bf(float f) {
    unsigned int u = __float_as_uint(f);
    u = (u + 0x7fffu + ((u >> 16) & 1u)) >> 16;
    return (unsigned short)u;
}

// ---------------- radix partition P1a: per-(wg,bucket) histogram ----------------
__global__ __launch_bounds__(256) void hist_k(const int* __restrict__ col, int* __restrict__ hist) {
    __shared__ int lh[NB1];
    int t = threadIdx.x, w = blockIdx.x;
    for (int i = t; i < NB1; i += 256) lh[i] = 0;
    __syncthreads();
    int base = w * EPB;
    int lim = min(base + EPB, NE);
#pragma unroll 4
    for (int e = base + t; e < lim; e += 256) atomicAdd(&lh[col[e] >> B1SH], 1);
    __syncthreads();
    for (int i = t; i < NB1; i += 256) hist[i * NWG1 + w] = lh[i];
}

// ---------------- bucket totals + exclusive scan -> bbase (one block) ----------------
__global__ __launch_bounds__(512) void btot_k(const int* __restrict__ hist, int* __restrict__ bbase) {
    __shared__ int tmp[512];
    int t = threadIdx.x;
    int s = 0;
    if (t < NB1) {
        const int* hp = hist + t * NWG1;
        for (int w = 0; w < NWG1; ++w) s += hp[w];
    }
    tmp[t] = s;
    __syncthreads();
    for (int o = 1; o < 512; o <<= 1) {
        int v = (t >= o) ? tmp[t - o] : 0;
        __syncthreads();
        tmp[t] += v;
        __syncthreads();
    }
    if (t < NB1) bbase[t] = tmp[t] - s;
    if (t == 511) bbase[NB1] = tmp[511];  // == NE
}

// ---------------- P1b: per-bucket exclusive scan over wgs, seeded by bbase[b] ----------------
__global__ __launch_bounds__(256) void histscan_k(const int* __restrict__ bbase, int* __restrict__ hist) {
    __shared__ int tmp[256];
    int b = blockIdx.x, t = threadIdx.x;
    int v = (t < NWG1) ? hist[b * NWG1 + t] : 0;
    tmp[t] = v;
    __syncthreads();
    for (int o = 1; o < 256; o <<= 1) {
        int u = (t >= o) ? tmp[t - o] : 0;
        __syncthreads();
        tmp[t] += u;
        __syncthreads();
    }
    int excl = tmp[t] - v;
    if (t < NWG1) hist[b * NWG1 + t] = bbase[b] + excl;
}

// ---------------- P1c: partition edges into coarse-bucket segments (packed) ----------------
__global__ __launch_bounds__(256) void part1_k(const int* __restrict__ row, const int* __restrict__ col,
                                               const int* __restrict__ hist, int* __restrict__ tmpe) {
    __shared__ int lcur[NB1];
    int t = threadIdx.x, w = blockIdx.x;
    for (int i = t; i < NB1; i += 256) lcur[i] = hist[i * NWG1 + w];
    __syncthreads();
    int base = w * EPB;
    int lim = min(base + EPB, NE);
#pragma unroll 4
    for (int e = base + t; e < lim; e += 256) {
        int c = col[e];
        int pos = atomicAdd(&lcur[c >> B1SH], 1);
        tmpe[pos] = (row[e] << B1SH) | (c & 255);  // src<2^17 -> 25 bits
    }
}

// ---------------- P2: count local degrees, write offs+dinv, scatter to exact CSR ----------------
__global__ __launch_bounds__(512) void part2b_k(const int* __restrict__ bbase, const int* __restrict__ tmpe,
                                                int* __restrict__ csr_src, int* __restrict__ offs,
                                                float* __restrict__ dinv) {
    __shared__ int lcnt[256];
    __shared__ int lsc[256];
    int b = blockIdx.x, t = threadIdx.x;
    if (t < 256) lcnt[t] = 0;
    __syncthreads();
    int ebeg = bbase[b], eend = bbase[b + 1];
    for (int e = ebeg + t; e < eend; e += 512) atomicAdd(&lcnt[tmpe[e] & 255], 1);
    __syncthreads();
    if (t < 256) lsc[t] = lcnt[t];
    __syncthreads();
    for (int o = 1; o < 256; o <<= 1) {
        int v = (t < 256 && t >= o) ? lsc[t - o] : 0;
        __syncthreads();
        if (t < 256) lsc[t] += v;
        __syncthreads();
    }
    int n0 = b << B1SH;
    if (t < 256) {
        int node = n0 + t;
        if (node < NN) {
            int excl = lsc[t] - lcnt[t];
            offs[node] = ebeg + excl;
            dinv[node] = rsqrtf((float)lcnt[t] + 1.0f);  // +1 self-loop
        }
    }
    if (b == NB1 - 1 && t == 0) offs[NN] = NE;
    __syncthreads();
    if (t < 256) lsc[t] = ebeg + (lsc[t] - lcnt[t]);  // cursors
    __syncthreads();
    for (int e = ebeg + t; e < eend; e += 512) {
        int p = tmpe[e];
        int pos = atomicAdd(&lsc[p & 255], 1);
        csr_src[pos] = p >> B1SH;
    }
}

// ---------------- W pack: fp32 [K=128][N=128] -> bf16 MFMA B-fragment order ----------------
// frag(n, kk, lane, j): k = kk*32 + (lane>>4)*8 + j, col = n*16 + (lane&15)
__global__ __launch_bounds__(256) void pack_w_k(const float* __restrict__ W, unsigned short* __restrict__ Wpk) {
    int t = threadIdx.x;
    for (int f = t * 64; f < t * 64 + 64; ++f) {
        int j = f & 7, lane = (f >> 3) & 63, kk = (f >> 9) & 3, n = f >> 11;
        int k = kk * 32 + ((lane >> 4) << 3) + j;
        int c = n * 16 + (lane & 15);
        Wpk[f] = f2bf(W[k * DD + c]);
    }
}

// ---------------- MFMA GEMM: outb[r][:] = bf16( dinv[r] * (X[r][:] @ W) ) ----------------
template <int IN_BF16>
__global__ __launch_bounds__(256) void gemm_mfma_k(const void* __restrict__ Xv,
                                                   const unsigned short* __restrict__ Wpk,
                                                   const float* __restrict__ dinv,
                                                   unsigned short* __restrict__ outb) {
    __shared__ unsigned short wlds[16384];  // 32 KB
    int tid = threadIdx.x;
    const uint4* wg = (const uint4*)Wpk;
    uint4* wl = (uint4*)wlds;
#pragma unroll
    for (int i = 0; i < 8; ++i) wl[tid + i * 256] = wg[tid + i * 256];
    __syncthreads();

    int w = tid >> 6, lane = tid & 63;
    int kg = lane >> 4;  // 0..3
    int rowbase = blockIdx.x * 64 + w * 16;
    int rl = min(rowbase + (lane & 15), NN - 1);

    short8v a[4];
    if (IN_BF16) {
        const unsigned short* xb = (const unsigned short*)Xv;
#pragma unroll
        for (int kk = 0; kk < 4; ++kk)
            a[kk] = *(const short8v*)(xb + (long)rl * DD + kk * 32 + kg * 8);
    } else {
        const float* xf = (const float*)Xv;
#pragma unroll
        for (int kk = 0; kk < 4; ++kk) {
            float4 f0 = *(const float4*)(xf + (long)rl * DD + kk * 32 + kg * 8);
            float4 f1 = *(const float4*)(xf + (long)rl * DD + kk * 32 + kg * 8 + 4);
            short8v t;
            t[0] = (short)f2bf(f0.x); t[1] = (short)f2bf(f0.y);
            t[2] = (short)f2bf(f0.z); t[3] = (short)f2bf(f0.w);
            t[4] = (short)f2bf(f1.x); t[5] = (short)f2bf(f1.y);
            t[6] = (short)f2bf(f1.z); t[7] = (short)f2bf(f1.w);
            a[kk] = t;
        }
    }

    f32x4 acc[8];
#pragma unroll
    for (int n = 0; n < 8; ++n) acc[n] = (f32x4){0.f, 0.f, 0.f, 0.f};
#pragma unroll
    for (int n = 0; n < 8; ++n) {
#pragma unroll
        for (int kk = 0; kk < 4; ++kk) {
            short8v b = *(const short8v*)(wlds + ((n * 4 + kk) * 64 + lane) * 8);
            acc[n] = __builtin_amdgcn_mfma_f32_16x16x32_bf16(a[kk], b, acc[n], 0, 0, 0);
        }
    }

    // D: col = n*16 + (lane&15), row = rowbase + kg*4 + reg
    int c0 = lane & 15;
#pragma unroll
    for (int reg = 0; reg < 4; ++reg) {
        int row = rowbase + kg * 4 + reg;
        if (row < NN) {
            float dv = dinv[row];
            unsigned short* op = outb + (long)row * DD + c0;
#pragma unroll
            for (int n = 0; n < 8; ++n) op[n * 16] = f2bf(dv * acc[n][reg]);
        }
    }
}

// ---------------- aggregation: wave per node, bf16 gather, fp32 accumulate, unroll 8 ----------------
__global__ __launch_bounds__(256) void agg_k(const unsigned short* __restrict__ hpb_,
                                             const float* __restrict__ dinv,
                                             const int* __restrict__ offs, const int* __restrict__ csr_src,
                                             const float* __restrict__ bias,
                                             unsigned short* __restrict__ outb) {
    int node = (blockIdx.x << 2) + (threadIdx.x >> 6);
    if (node >= NN) return;
    int lane = threadIdx.x & 63;
    const unsigned int* hpb = (const unsigned int*)hpb_;  // 2 bf16 per uint
    int s = offs[node];
    int e_end = offs[node + 1];
    unsigned int ps = hpb[(long)node * 64 + lane];  // self-loop
    float accx = __uint_as_float(ps << 16);
    float accy = __uint_as_float(ps & 0xffff0000u);
    int e = s;
    for (; e + 8 <= e_end; e += 8) {
        int i0 = csr_src[e];     int i1 = csr_src[e + 1];
        int i2 = csr_src[e + 2]; int i3 = csr_src[e + 3];
        int i4 = csr_src[e + 4]; int i5 = csr_src[e + 5];
        int i6 = csr_src[e + 6]; int i7 = csr_src[e + 7];
        unsigned int p0 = hpb[(long)i0 * 64 + lane];
        unsigned int p1 = hpb[(long)i1 * 64 + lane];
        unsigned int p2 = hpb[(long)i2 * 64 + lane];
        unsigned int p3 = hpb[(long)i3 * 64 + lane];
        unsigned int p4 = hpb[(long)i4 * 64 + lane];
        unsigned int p5 = hpb[(long)i5 * 64 + lane];
        unsigned int p6 = hpb[(long)i6 * 64 + lane];
        unsigned int p7 = hpb[(long)i7 * 64 + lane];
        accx += (__uint_as_float(p0 << 16) + __uint_as_float(p1 << 16)) +
                (__uint_as_float(p2 << 16) + __uint_as_float(p3 << 16)) +
                (__uint_as_float(p4 << 16) + __uint_as_float(p5 << 16)) +
                (__uint_as_float(p6 << 16) + __uint_as_float(p7 << 16));
        accy += (__uint_as_float(p0 & 0xffff0000u) + __uint_as_float(p1 & 0xffff0000u)) +
                (__uint_as_float(p2 & 0xffff0000u) + __uint_as_float(p3 & 0xffff0000u)) +
                (__uint_as_float(p4 & 0xffff0000u) + __uint_as_float(p5 & 0xffff0000u)) +
                (__uint_as_float(p6 & 0xffff0000u) + __uint_as_float(p7 & 0xffff0000u));
    }
    if (e + 4 <= e_end) {
        int i0 = csr_src[e];     int i1 = csr_src[e + 1];
        int i2 = csr_src[e + 2]; int i3 = csr_src[e + 3];
        unsigned int p0 = hpb[(long)i0 * 64 + lane];
        unsigned int p1 = hpb[(long)i1 * 64 + lane];
        unsigned int p2 = hpb[(long)i2 * 64 + lane];
        unsigned int p3 = hpb[(long)i3 * 64 + lane];
        accx += (__uint_as_float(p0 << 16) + __uint_as_float(p1 << 16)) +
                (__uint_as_float(p2 << 16) + __uint_as_float(p3 << 16));
        accy += (__uint_as_float(p0 & 0xffff0000u) + __uint_as_float(p1 & 0xffff0000u)) +
                (__uint_as_float(p2 & 0xffff0000u) + __uint_as_float(p3 & 0xffff0000u));
        e += 4;
    }
    for (; e < e_end; ++e) {
        unsigned int p0 = hpb[(long)csr_src[e] * 64 + lane];
        accx += __uint_as_float(p0 << 16);
        accy += __uint_as_float(p0 & 0xffff0000u);
    }
    float dv = dinv[node];
    float2 b = ((const float2*)bias)[lane];
    float ox = fmaxf(fmaf(dv, accx, b.x), 0.0f);
    float oy = fmaxf(fmaf(dv, accy, b.y), 0.0f);
    ((ushort2*)outb)[(long)node * 64 + lane] = make_ushort2(f2bf(ox), f2bf(oy));
}

// ---------------- pooling: 2048 waves over sorted batch (bf16 in), boundary-flush atomics ----------------
__global__ __launch_bounds__(256) void pool2_k(const unsigned short* __restrict__ h,
                                               const int* __restrict__ batch,
                                               float* __restrict__ gsum) {
    int wave = (blockIdx.x * 256 + threadIdx.x) >> 6;
    int lane = threadIdx.x & 63;
    const int per = (NN + POOL_WAVES - 1) / POOL_WAVES;  // 49
    int s = wave * per;
    int e = min(s + per, NN);
    if (s >= e) return;
    const unsigned int* h2 = (const unsigned int*)h;
    float2 acc = {0.0f, 0.0f};
    int cur = batch[s];
    for (int r = s; r < e; ++r) {
        int b = batch[r];
        if (b != cur) {
            atomicAdd(&gsum[cur * DD + 2 * lane], acc.x);
            atomicAdd(&gsum[cur * DD + 2 * lane + 1], acc.y);
            acc.x = 0.0f; acc.y = 0.0f;
            cur = b;
        }
        unsigned int v = h2[(long)r * 64 + lane];
        acc.x += __uint_as_float(v << 16);
        acc.y += __uint_as_float(v & 0xffff0000u);
    }
    atomicAdd(&gsum[cur * DD + 2 * lane], acc.x);
    atomicAdd(&gsum[cur * DD + 2 * lane + 1], acc.y);
}

// ---------------- graph boundaries (batch sorted) ----------------
__global__ __launch_bounds__(256) void starts_k(const int* __restrict__ batch, int* __restrict__ starts) {
    int g = threadIdx.x;
    if (g > NG) return;
    if (g == NG) {
        starts[NG] = NN;
        return;
    }
    int lo = 0, hi = NN;
    while (lo < hi) {
        int mid = (lo + hi) >> 1;
        if (batch[mid] < g) lo = mid + 1;
        else hi = mid;
    }
    starts[g] = lo;
}

__global__ __launch_bounds__(256) void final_k(const float* __restrict__ gsum, const int* __restrict__ starts,
                                               const float* __restrict__ Wlin, const float* __restrict__ blin,
                                               float* __restrict__ out) {
    int idx = blockIdx.x * 256 + threadIdx.x;
    if (idx >= NG * NC) return;
    int g = idx / NC, c = idx % NC;
    int cnt = starts[g + 1] - starts[g];
    float inv = 1.0f / fmaxf((float)cnt, 1.0f);
    float acc = blin[c];
    for (int k = 0; k < DD; ++k) acc = fmaf(gsum[g * DD + k] * inv, Wlin[k * NC + c], acc);
    out[idx] = acc;
}

extern "C" void kernel_launch(void* const* d_in, const int* in_sizes, int n_in,
                              void* d_out, int out_size, void* d_ws, size_t ws_size,
                              hipStream_t stream) {
    const float* x     = (const float*)d_in[0];
    const int*   ei    = (const int*)d_in[1];   // [2][NE]: row=src, col=dst
    const int*   batch = (const int*)d_in[2];
    const float* W1    = (const float*)d_in[3];
    const float* b1    = (const float*)d_in[4];
    const float* W2    = (const float*)d_in[5];
    const float* b2    = (const float*)d_in[6];
    const float* Wlin  = (const float*)d_in[7];
    const float* blin  = (const float*)d_in[8];
    float* out = (float*)d_out;

    const int* erow = ei;
    const int* ecol = ei + NE;

    char* ws = (char*)d_ws;
    size_t off = 0;
    auto alloc = [&](size_t bytes) {
        void* p = ws + off;
        off = (off + bytes + 255) & ~(size_t)255;
        return p;
    };
    unsigned short* hbuf  = (unsigned short*)alloc((size_t)NN * DD * 2);  // gemm out h' (bf16)
    unsigned short* habuf = (unsigned short*)alloc((size_t)NN * DD * 2);  // agg out (bf16)
    unsigned short* Wpk1  = (unsigned short*)alloc(16384 * 2);
    unsigned short* Wpk2  = (unsigned short*)alloc(16384 * 2);
    float* dinv     = (float*)alloc(NN * 4);
    int*   offs     = (int*)alloc((NN + 1) * 4);
    int*   bbase    = (int*)alloc((NB1 + 1) * 4);
    int*   hist     = (int*)alloc((size_t)NB1 * NWG1 * 4);
    int*   tmpe     = (int*)alloc((size_t)NE * 4);
    int*   csrsrc   = (int*)alloc((size_t)NE * 4);
    float* gsum     = (float*)alloc(NG * DD * 4);
    int*   starts   = (int*)alloc((NG + 1) * 4);
    (void)ws_size; (void)in_sizes; (void)n_in; (void)out_size;

    hipMemsetAsync(gsum, 0, NG * DD * 4, stream);

    hist_k<<<NWG1, 256, 0, stream>>>(ecol, hist);
    btot_k<<<1, 512, 0, stream>>>(hist, bbase);
    histscan_k<<<NB1, 256, 0, stream>>>(bbase, hist);
    part1_k<<<NWG1, 256, 0, stream>>>(erow, ecol, hist, tmpe);
    part2b_k<<<NB1, 512, 0, stream>>>(bbase, tmpe, csrsrc, offs, dinv);

    pack_w_k<<<1, 256, 0, stream>>>(W1, Wpk1);
    pack_w_k<<<1, 256, 0, stream>>>(W2, Wpk2);

    int gblocks = (NN + 63) / 64;  // 1563
    // layer 1: x (fp32) -> hbuf (bf16 h') -> habuf (bf16 agg+relu)
    gemm_mfma_k<0><<<gblocks, 256, 0, stream>>>(x, Wpk1, dinv, hbuf);
    agg_k<<<(NN + 3) / 4, 256, 0, stream>>>(hbuf, dinv, offs, csrsrc, b1, habuf);
    // layer 2: habuf (bf16) -> hbuf (bf16 h') -> habuf (bf16 agg+relu)
    gemm_mfma_k<1><<<gblocks, 256, 0, stream>>>(habuf, Wpk2, dinv, hbuf);
    agg_k<<<(NN + 3) / 4, 256, 0, stream>>>(hbuf, dinv, offs, csrsrc, b2, habuf);

    // pooling + head
    starts_k<<<1, 256, 0, stream>>>(batch, starts);
    pool2_k<<<POOL_WAVES / 4, 256, 0, stream>>>(habuf, batch, gsum);
    final_k<<<(NG * NC + 255) / 256, 256, 0, stream>>>(gsum, starts, Wlin, blin, out);
}

// Round 11
// 270.066 us; speedup vs baseline: 12.0803x; 1.0327x over previous
//
#include <hip/hip_runtime.h>

#define NN 100000
#define NE 1600000
#define DD 128
#define NG 128
#define NC 10
#define POOL_WAVES 2048

#define B1SH 8                        // coarse bucket = 256 nodes
#define NB1 ((NN + 255) / 256)        // 391 buckets
#define EPB 8192                      // edges per partition block
#define NWG1 ((NE + EPB - 1) / EPB)   // 196 partition blocks

typedef __attribute__((ext_vector_type(8))) short short8v;   // 8 bf16 (4 VGPRs)
typedef __attribute__((ext_vector_type(4))) float f32x4;     // MFMA acc

// fp32 -> bf16 round-to-nearest-even
__device__ __forceinline__ unsigned short f2bf(float f) {
    unsigned int u = __float_as_uint(f);
    u = (u + 0x7fffu + ((u >> 16) & 1u)) >> 16;
    return (unsigned short)u;
}

// ---------------- radix partition P1a: per-(wg,bucket) histogram ----------------
__global__ __launch_bounds__(256) void hist_k(const int* __restrict__ col, int* __restrict__ hist) {
    __shared__ int lh[NB1];
    int t = threadIdx.x, w = blockIdx.x;
    for (int i = t; i < NB1; i += 256) lh[i] = 0;
    __syncthreads();
    int base = w * EPB;
    int lim = min(base + EPB, NE);
#pragma unroll 4
    for (int e = base + t; e < lim; e += 256) atomicAdd(&lh[col[e] >> B1SH], 1);
    __syncthreads();
    for (int i = t; i < NB1; i += 256) hist[i * NWG1 + w] = lh[i];
}

// ---------------- bucket totals + exclusive scan -> bbase (one block) ----------------
__global__ __launch_bounds__(512) void btot_k(const int* __restrict__ hist, int* __restrict__ bbase) {
    __shared__ int tmp[512];
    int t = threadIdx.x;
    int s = 0;
    if (t < NB1) {
        const int* hp = hist + t * NWG1;
        for (int w = 0; w < NWG1; ++w) s += hp[w];
    }
    tmp[t] = s;
    __syncthreads();
    for (int o = 1; o < 512; o <<= 1) {
        int v = (t >= o) ? tmp[t - o] : 0;
        __syncthreads();
        tmp[t] += v;
        __syncthreads();
    }
    if (t < NB1) bbase[t] = tmp[t] - s;
    if (t == 511) bbase[NB1] = tmp[511];  // == NE
}

// ---------------- P1b: per-bucket exclusive scan over wgs, seeded by bbase[b] ----------------
__global__ __launch_bounds__(256) void histscan_k(const int* __restrict__ bbase, int* __restrict__ hist) {
    __shared__ int tmp[256];
    int b = blockIdx.x, t = threadIdx.x;
    int v = (t < NWG1) ? hist[b * NWG1 + t] : 0;
    tmp[t] = v;
    __syncthreads();
    for (int o = 1; o < 256; o <<= 1) {
        int u = (t >= o) ? tmp[t - o] : 0;
        __syncthreads();
        tmp[t] += u;
        __syncthreads();
    }
    int excl = tmp[t] - v;
    if (t < NWG1) hist[b * NWG1 + t] = bbase[b] + excl;
}

// ---------------- P1c: partition edges into coarse-bucket segments (packed) ----------------
__global__ __launch_bounds__(256) void part1_k(const int* __restrict__ row, const int* __restrict__ col,
                                               const int* __restrict__ hist, int* __restrict__ tmpe) {
    __shared__ int lcur[NB1];
    int t = threadIdx.x, w = blockIdx.x;
    for (int i = t; i < NB1; i += 256) lcur[i] = hist[i * NWG1 + w];
    __syncthreads();
    int base = w * EPB;
    int lim = min(base + EPB, NE);
#pragma unroll 4
    for (int e = base + t; e < lim; e += 256) {
        int c = col[e];
        int pos = atomicAdd(&lcur[c >> B1SH], 1);
        tmpe[pos] = (row[e] << B1SH) | (c & 255);  // src<2^17 -> 25 bits
    }
}

// ---------------- P2: count local degrees, write offs+dinv, scatter to exact CSR ----------------
// csr_src stores src*64 (uint-index into the 2-bf16-per-uint row array)
__global__ __launch_bounds__(512) void part2b_k(const int* __restrict__ bbase, const int* __restrict__ tmpe,
                                                unsigned int* __restrict__ csr_src, int* __restrict__ offs,
                                                float* __restrict__ dinv) {
    __shared__ int lcnt[256];
    __shared__ int lsc[256];
    int b = blockIdx.x, t = threadIdx.x;
    if (t < 256) lcnt[t] = 0;
    __syncthreads();
    int ebeg = bbase[b], eend = bbase[b + 1];
    for (int e = ebeg + t; e < eend; e += 512) atomicAdd(&lcnt[tmpe[e] & 255], 1);
    __syncthreads();
    if (t < 256) lsc[t] = lcnt[t];
    __syncthreads();
    for (int o = 1; o < 256; o <<= 1) {
        int v = (t < 256 && t >= o) ? lsc[t - o] : 0;
        __syncthreads();
        if (t < 256) lsc[t] += v;
        __syncthreads();
    }
    int n0 = b << B1SH;
    if (t < 256) {
        int node = n0 + t;
        if (node < NN) {
            int excl = lsc[t] - lcnt[t];
            offs[node] = ebeg + excl;
            dinv[node] = rsqrtf((float)lcnt[t] + 1.0f);  // +1 self-loop
        }
    }
    if (b == NB1 - 1 && t == 0) offs[NN] = NE;
    __syncthreads();
    if (t < 256) lsc[t] = ebeg + (lsc[t] - lcnt[t]);  // cursors
    __syncthreads();
    for (int e = ebeg + t; e < eend; e += 512) {
        int p = tmpe[e];
        int pos = atomicAdd(&lsc[p & 255], 1);
        csr_src[pos] = (unsigned int)(p >> B1SH) << 6;  // src*64
    }
}

// ---------------- W pack (both weights): fp32 [K=128][N=128] -> bf16 MFMA B-frag order ----------------
// frag(n, kk, lane, j): k = kk*32 + (lane>>4)*8 + j, col = n*16 + (lane&15)
__global__ __launch_bounds__(256) void pack_w2_k(const float* __restrict__ W1, const float* __restrict__ W2,
                                                 unsigned short* __restrict__ Wpk1,
                                                 unsigned short* __restrict__ Wpk2) {
    const float* W = blockIdx.x ? W2 : W1;
    unsigned short* Wpk = blockIdx.x ? Wpk2 : Wpk1;
    int t = threadIdx.x;
    for (int f = t * 64; f < t * 64 + 64; ++f) {
        int j = f & 7, lane = (f >> 3) & 63, kk = (f >> 9) & 3, n = f >> 11;
        int k = kk * 32 + ((lane >> 4) << 3) + j;
        int c = n * 16 + (lane & 15);
        Wpk[f] = f2bf(W[k * DD + c]);
    }
}

// ---------------- MFMA GEMM: outb[r][:] = bf16( dinv[r] * (X[r][:] @ W) ) ----------------
template <int IN_BF16>
__global__ __launch_bounds__(256) void gemm_mfma_k(const void* __restrict__ Xv,
                                                   const unsigned short* __restrict__ Wpk,
                                                   const float* __restrict__ dinv,
                                                   unsigned short* __restrict__ outb) {
    __shared__ unsigned short wlds[16384];  // 32 KB
    int tid = threadIdx.x;
    const uint4* wg = (const uint4*)Wpk;
    uint4* wl = (uint4*)wlds;
#pragma unroll
    for (int i = 0; i < 8; ++i) wl[tid + i * 256] = wg[tid + i * 256];
    __syncthreads();

    int w = tid >> 6, lane = tid & 63;
    int kg = lane >> 4;  // 0..3
    int rowbase = blockIdx.x * 64 + w * 16;
    int rl = min(rowbase + (lane & 15), NN - 1);

    short8v a[4];
    if (IN_BF16) {
        const unsigned short* xb = (const unsigned short*)Xv;
#pragma unroll
        for (int kk = 0; kk < 4; ++kk)
            a[kk] = *(const short8v*)(xb + (long)rl * DD + kk * 32 + kg * 8);
    } else {
        const float* xf = (const float*)Xv;
#pragma unroll
        for (int kk = 0; kk < 4; ++kk) {
            float4 f0 = *(const float4*)(xf + (long)rl * DD + kk * 32 + kg * 8);
            float4 f1 = *(const float4*)(xf + (long)rl * DD + kk * 32 + kg * 8 + 4);
            short8v t;
            t[0] = (short)f2bf(f0.x); t[1] = (short)f2bf(f0.y);
            t[2] = (short)f2bf(f0.z); t[3] = (short)f2bf(f0.w);
            t[4] = (short)f2bf(f1.x); t[5] = (short)f2bf(f1.y);
            t[6] = (short)f2bf(f1.z); t[7] = (short)f2bf(f1.w);
            a[kk] = t;
        }
    }

    f32x4 acc[8];
#pragma unroll
    for (int n = 0; n < 8; ++n) acc[n] = (f32x4){0.f, 0.f, 0.f, 0.f};
#pragma unroll
    for (int n = 0; n < 8; ++n) {
#pragma unroll
        for (int kk = 0; kk < 4; ++kk) {
            short8v b = *(const short8v*)(wlds + ((n * 4 + kk) * 64 + lane) * 8);
            acc[n] = __builtin_amdgcn_mfma_f32_16x16x32_bf16(a[kk], b, acc[n], 0, 0, 0);
        }
    }

    // D: col = n*16 + (lane&15), row = rowbase + kg*4 + reg
    int c0 = lane & 15;
#pragma unroll
    for (int reg = 0; reg < 4; ++reg) {
        int row = rowbase + kg * 4 + reg;
        if (row < NN) {
            float dv = dinv[row];
            unsigned short* op = outb + (long)row * DD + c0;
#pragma unroll
            for (int n = 0; n < 8; ++n) op[n * 16] = f2bf(dv * acc[n][reg]);
        }
    }
}

// ---------------- aggregation: wave per node, bf16 gather via 32-bit voffset, fp32 acc ----------------
__global__ __launch_bounds__(256) void agg_k(const unsigned int* __restrict__ hpb,
                                             const float* __restrict__ dinv,
                                             const int* __restrict__ offs,
                                             const unsigned int* __restrict__ csr,
                                             const float* __restrict__ bias,
                                             unsigned short* __restrict__ outb) {
    int node = (blockIdx.x << 2) + (threadIdx.x >> 6);
    if (node >= NN) return;
    unsigned int lane = threadIdx.x & 63;
    int s = offs[node];
    int e_end = offs[node + 1];
    unsigned int ps = hpb[(unsigned int)node * 64u + lane];  // self-loop
    float accx = __uint_as_float(ps << 16);
    float accy = __uint_as_float(ps & 0xffff0000u);
    int e = s;
    for (; e + 8 <= e_end; e += 8) {
        unsigned int i0 = csr[e] + lane;     unsigned int i1 = csr[e + 1] + lane;
        unsigned int i2 = csr[e + 2] + lane; unsigned int i3 = csr[e + 3] + lane;
        unsigned int i4 = csr[e + 4] + lane; unsigned int i5 = csr[e + 5] + lane;
        unsigned int i6 = csr[e + 6] + lane; unsigned int i7 = csr[e + 7] + lane;
        unsigned int p0 = hpb[i0];
        unsigned int p1 = hpb[i1];
        unsigned int p2 = hpb[i2];
        unsigned int p3 = hpb[i3];
        unsigned int p4 = hpb[i4];
        unsigned int p5 = hpb[i5];
        unsigned int p6 = hpb[i6];
        unsigned int p7 = hpb[i7];
        accx += (__uint_as_float(p0 << 16) + __uint_as_float(p1 << 16)) +
                (__uint_as_float(p2 << 16) + __uint_as_float(p3 << 16)) +
                (__uint_as_float(p4 << 16) + __uint_as_float(p5 << 16)) +
                (__uint_as_float(p6 << 16) + __uint_as_float(p7 << 16));
        accy += (__uint_as_float(p0 & 0xffff0000u) + __uint_as_float(p1 & 0xffff0000u)) +
                (__uint_as_float(p2 & 0xffff0000u) + __uint_as_float(p3 & 0xffff0000u)) +
                (__uint_as_float(p4 & 0xffff0000u) + __uint_as_float(p5 & 0xffff0000u)) +
                (__uint_as_float(p6 & 0xffff0000u) + __uint_as_float(p7 & 0xffff0000u));
    }
    if (e + 4 <= e_end) {
        unsigned int p0 = hpb[csr[e] + lane];
        unsigned int p1 = hpb[csr[e + 1] + lane];
        unsigned int p2 = hpb[csr[e + 2] + lane];
        unsigned int p3 = hpb[csr[e + 3] + lane];
        accx += (__uint_as_float(p0 << 16) + __uint_as_float(p1 << 16)) +
                (__uint_as_float(p2 << 16) + __uint_as_float(p3 << 16));
        accy += (__uint_as_float(p0 & 0xffff0000u) + __uint_as_float(p1 & 0xffff0000u)) +
                (__uint_as_float(p2 & 0xffff0000u) + __uint_as_float(p3 & 0xffff0000u));
        e += 4;
    }
    for (; e < e_end; ++e) {
        unsigned int p0 = hpb[csr[e] + lane];
        accx += __uint_as_float(p0 << 16);
        accy += __uint_as_float(p0 & 0xffff0000u);
    }
    float dv = dinv[node];
    float2 b = ((const float2*)bias)[lane];
    float ox = fmaxf(fmaf(dv, accx, b.x), 0.0f);
    float oy = fmaxf(fmaf(dv, accy, b.y), 0.0f);
    ((ushort2*)outb)[(unsigned int)node * 64u + lane] = make_ushort2(f2bf(ox), f2bf(oy));
}

// ---------------- pooling: 2048 waves over sorted batch (bf16 in), boundary-flush atomics ----------------
__global__ __launch_bounds__(256) void pool2_k(const unsigned short* __restrict__ h,
                                               const int* __restrict__ batch,
                                               float* __restrict__ gsum) {
    int wave = (blockIdx.x * 256 + threadIdx.x) >> 6;
    int lane = threadIdx.x & 63;
    const int per = (NN + POOL_WAVES - 1) / POOL_WAVES;  // 49
    int s = wave * per;
    int e = min(s + per, NN);
    if (s >= e) return;
    const unsigned int* h2 = (const unsigned int*)h;
    float2 acc = {0.0f, 0.0f};
    int cur = batch[s];
    for (int r = s; r < e; ++r) {
        int b = batch[r];
        if (b != cur) {
            atomicAdd(&gsum[cur * DD + 2 * lane], acc.x);
            atomicAdd(&gsum[cur * DD + 2 * lane + 1], acc.y);
            acc.x = 0.0f; acc.y = 0.0f;
            cur = b;
        }
        unsigned int v = h2[(unsigned int)r * 64u + lane];
        acc.x += __uint_as_float(v << 16);
        acc.y += __uint_as_float(v & 0xffff0000u);
    }
    atomicAdd(&gsum[cur * DD + 2 * lane], acc.x);
    atomicAdd(&gsum[cur * DD + 2 * lane + 1], acc.y);
}

// ---------------- final head: inline graph-boundary binary search ----------------
__global__ __launch_bounds__(256) void final_k(const float* __restrict__ gsum, const int* __restrict__ batch,
                                               const float* __restrict__ Wlin, const float* __restrict__ blin,
                                               float* __restrict__ out) {
    int idx = blockIdx.x * 256 + threadIdx.x;
    if (idx >= NG * NC) return;
    int g = idx / NC, c = idx % NC;
    // lower_bound(batch, g) and lower_bound(batch, g+1)
    int s0, s1;
    {
        int lo = 0, hi = NN;
        while (lo < hi) { int m = (lo + hi) >> 1; if (batch[m] < g) lo = m + 1; else hi = m; }
        s0 = lo;
        lo = s0; hi = NN;
        while (lo < hi) { int m = (lo + hi) >> 1; if (batch[m] < g + 1) lo = m + 1; else hi = m; }
        s1 = lo;
    }
    int cnt = s1 - s0;
    float inv = 1.0f / fmaxf((float)cnt, 1.0f);
    float acc = blin[c];
    for (int k = 0; k < DD; ++k) acc = fmaf(gsum[g * DD + k] * inv, Wlin[k * NC + c], acc);
    out[idx] = acc;
}

extern "C" void kernel_launch(void* const* d_in, const int* in_sizes, int n_in,
                              void* d_out, int out_size, void* d_ws, size_t ws_size,
                              hipStream_t stream) {
    const float* x     = (const float*)d_in[0];
    const int*   ei    = (const int*)d_in[1];   // [2][NE]: row=src, col=dst
    const int*   batch = (const int*)d_in[2];
    const float* W1    = (const float*)d_in[3];
    const float* b1    = (const float*)d_in[4];
    const float* W2    = (const float*)d_in[5];
    const float* b2    = (const float*)d_in[6];
    const float* Wlin  = (const float*)d_in[7];
    const float* blin  = (const float*)d_in[8];
    float* out = (float*)d_out;

    const int* erow = ei;
    const int* ecol = ei + NE;

    char* ws = (char*)d_ws;
    size_t off = 0;
    auto alloc = [&](size_t bytes) {
        void* p = ws + off;
        off = (off + bytes + 255) & ~(size_t)255;
        return p;
    };
    unsigned short* hbuf  = (unsigned short*)alloc((size_t)NN * DD * 2);  // gemm out h' (bf16)
    unsigned short* habuf = (unsigned short*)alloc((size_t)NN * DD * 2);  // agg out (bf16)
    unsigned short* Wpk1  = (unsigned short*)alloc(16384 * 2);
    unsigned short* Wpk2  = (unsigned short*)alloc(16384 * 2);
    float* dinv     = (float*)alloc(NN * 4);
    int*   offs     = (int*)alloc((NN + 1) * 4);
    int*   bbase    = (int*)alloc((NB1 + 1) * 4);
    int*   hist     = (int*)alloc((size_t)NB1 * NWG1 * 4);
    int*   tmpe     = (int*)alloc((size_t)NE * 4);
    unsigned int* csrsrc = (unsigned int*)alloc((size_t)NE * 4);
    float* gsum     = (float*)alloc(NG * DD * 4);
    (void)ws_size; (void)in_sizes; (void)n_in; (void)out_size;

    hipMemsetAsync(gsum, 0, NG * DD * 4, stream);

    hist_k<<<NWG1, 256, 0, stream>>>(ecol, hist);
    btot_k<<<1, 512, 0, stream>>>(hist, bbase);
    histscan_k<<<NB1, 256, 0, stream>>>(bbase, hist);
    part1_k<<<NWG1, 256, 0, stream>>>(erow, ecol, hist, tmpe);
    part2b_k<<<NB1, 512, 0, stream>>>(bbase, tmpe, csrsrc, offs, dinv);

    pack_w2_k<<<2, 256, 0, stream>>>(W1, W2, Wpk1, Wpk2);

    int gblocks = (NN + 63) / 64;  // 1563
    // layer 1: x (fp32) -> hbuf (bf16 h') -> habuf (bf16 agg+relu)
    gemm_mfma_k<0><<<gblocks, 256, 0, stream>>>(x, Wpk1, dinv, hbuf);
    agg_k<<<(NN + 3) / 4, 256, 0, stream>>>((const unsigned int*)hbuf, dinv, offs, csrsrc, b1, habuf);
    // layer 2: habuf (bf16) -> hbuf (bf16 h') -> habuf (bf16 agg+relu)
    gemm_mfma_k<1><<<gblocks, 256, 0, stream>>>(habuf, Wpk2, dinv, hbuf);
    agg_k<<<(NN + 3) / 4, 256, 0, stream>>>((const unsigned int*)hbuf, dinv, offs, csrsrc, b2, habuf);

    // pooling + head
    pool2_k<<<POOL_WAVES / 4, 256, 0, stream>>>(habuf, batch, gsum);
    final_k<<<(NG * NC + 255) / 256, 256, 0, stream>>>(gsum, batch, Wlin, blin, out);
}